// Round 1
// baseline (777.563 us; speedup 1.0000x reference)
//
#include <hip/hip_runtime.h>

// LocalMatching fused kernel for MI355X (gfx950).
// Two cross-attentions sharing e = cs·rs^T (computed per-direction, flash-style),
// each fused with its FC head: out = relu(concat(q, o, q-o, q*o) · W^T + b).
// QK^T uses bf16x3 split (fp32-fidelity logits); PV and FC use plain bf16 MFMA.

#define NB  32
#define NLC 2048
#define NLR 512
#define ND  256
#define NH  128

typedef float f32x4 __attribute__((ext_vector_type(4)));
typedef short s16x8 __attribute__((ext_vector_type(8)));
typedef short s16x4 __attribute__((ext_vector_type(4)));

// LDS layout (bytes), single 64 KiB pool, phase-unioned:
//  KV phase: KH [0,16K) KL [16K,32K) VT [32K,48K) P [48K,52K)
//  FC phase: O  [0,32K)  W  [32K,64K)
#define SM_KH 0
#define SM_KL 16384
#define SM_VT 32768
#define SM_P  49152
#define SM_O  0
#define SM_W  32768

__device__ __forceinline__ unsigned short f2bf(float x){
  unsigned u = __builtin_bit_cast(unsigned, x);
  u += 0x7FFFu + ((u >> 16) & 1u);           // round-to-nearest-even
  return (unsigned short)(u >> 16);
}
__device__ __forceinline__ float bf2f(unsigned short h){
  unsigned u = ((unsigned)h) << 16;
  return __builtin_bit_cast(float, u);
}
__device__ __forceinline__ void splitbf(float x, short &hi, short &lo){
  unsigned short h = f2bf(x);
  float r = x - bf2f(h);
  hi = (short)h;
  lo = (short)f2bf(r);
}

__global__ __launch_bounds__(256, 2)
void lm_kernel(const float* __restrict__ cs, const float* __restrict__ rs,
               const float* __restrict__ W1, const float* __restrict__ b1,
               const float* __restrict__ W2, const float* __restrict__ b2,
               float* __restrict__ out)
{
  __shared__ __align__(16) char smem[65536];

  const int tid  = threadIdx.x;
  const int lane = tid & 63;
  const int wid  = tid >> 6;        // wave 0..3, owns q rows [16*wid, 16*wid+16)
  const int c    = lane & 15;       // MFMA col-lane
  const int g    = lane >> 4;       // MFMA quad group 0..3

  // ---- block decode with XCD-aware swizzle: batch-group (b>>2) pinned to one XCD
  int bid = blockIdx.x;
  int dir, b, qt;
  if (bid < 1024){ int xcd = bid & 7, inner = bid >> 3;
    b = (xcd << 2) + (inner >> 5); qt = inner & 31; dir = 0; }
  else { int t2 = bid - 1024; int xcd = t2 & 7, inner = t2 >> 3;
    b = (xcd << 2) + (inner >> 3); qt = inner & 7; dir = 1; }

  const float* Q   = dir == 0 ? cs + ((size_t)b*NLC + qt*64)*ND
                              : rs + ((size_t)b*NLR + qt*64)*ND;
  const float* KV  = dir == 0 ? rs + (size_t)b*NLR*ND : cs + (size_t)b*NLC*ND;
  const int    NK  = dir == 0 ? NLR : NLC;
  const float* Wm  = dir == 0 ? W1 : W2;
  const float* bia = dir == 0 ? b1 : b2;
  float* outp = dir == 0 ? out + ((size_t)b*NLC + qt*64)*NH
                         : out + (size_t)NB*NLC*NH + ((size_t)b*NLR + qt*64)*NH;

  // ---- Q fragments straight from global into registers (hi/lo split), held all kernel
  s16x8 qh[8], ql[8];
  {
    const float* qrow = Q + (size_t)(16*wid + c)*ND;
    #pragma unroll
    for (int ks = 0; ks < 8; ++ks){
      float4 x0 = *(const float4*)(qrow + 32*ks + 8*g);
      float4 x1 = *(const float4*)(qrow + 32*ks + 8*g + 4);
      float xs[8] = {x0.x,x0.y,x0.z,x0.w,x1.x,x1.y,x1.z,x1.w};
      #pragma unroll
      for (int j = 0; j < 8; ++j){ short h,l; splitbf(xs[j],h,l); qh[ks][j]=h; ql[ks][j]=l; }
    }
  }

  // ---- online-softmax state + O accumulator (D-layout: row = 4g+r, col = 16*dt+c)
  f32x4 o[16];
  #pragma unroll
  for (int i = 0; i < 16; ++i) o[i] = (f32x4){0.f,0.f,0.f,0.f};
  float m_run[4] = {-INFINITY,-INFINITY,-INFINITY,-INFINITY};
  float l_run[4] = {0.f,0.f,0.f,0.f};

  const int ntile = NK >> 5;
  for (int t = 0; t < ntile; ++t){
    __syncthreads();                               // protect K/V/P LDS overwrite
    // ---- stage 32 KV rows: K hi/lo row-major + V^T (hi) with swizzles
    {
      const float* KVt = KV + (size_t)t*32*ND;
      #pragma unroll
      for (int p = 0; p < 8; ++p){
        int kvloc = p*4 + wid;
        float4 x = *((const float4*)(KVt + kvloc*ND) + lane);   // full-row coalesced
        short h0,l0,h1,l1,h2,l2,h3,l3;
        splitbf(x.x,h0,l0); splitbf(x.y,h1,l1); splitbf(x.z,h2,l2); splitbf(x.w,h3,l3);
        int roff = kvloc*512 + ((8*lane) ^ ((kvloc&7)<<4));
        *(s16x4*)(smem + SM_KH + roff) = (s16x4){h0,h1,h2,h3};
        *(s16x4*)(smem + SM_KL + roff) = (s16x4){l0,l1,l2,l3};
        int d0 = 4*lane;
        short hs[4] = {h0,h1,h2,h3};
        #pragma unroll
        for (int j = 0; j < 4; ++j){
          int dr = d0 + j;
          int voff = dr*64 + ((2*kvloc) ^ (((dr>>2)&3)<<4));
          *(short*)(smem + SM_VT + voff) = hs[j];
        }
      }
    }
    __syncthreads();

    // ---- S = Q·K^T  (bf16x3: Qh·Kh + Ql·Kh + Qh·Kl), 2 n-tiles of 16 kv
    f32x4 s0 = (f32x4){0.f,0.f,0.f,0.f}, s1 = (f32x4){0.f,0.f,0.f,0.f};
    #pragma unroll
    for (int ks = 0; ks < 8; ++ks){
      int kb = 64*ks + 16*g;
      int r0 = c, r1 = 16 + c;
      int o0 = r0*512 + (kb ^ ((r0&7)<<4));
      int o1 = r1*512 + (kb ^ ((r1&7)<<4));
      s16x8 bh0 = *(const s16x8*)(smem + SM_KH + o0);
      s16x8 bl0 = *(const s16x8*)(smem + SM_KL + o0);
      s16x8 bh1 = *(const s16x8*)(smem + SM_KH + o1);
      s16x8 bl1 = *(const s16x8*)(smem + SM_KL + o1);
      s0 = __builtin_amdgcn_mfma_f32_16x16x32_bf16(qh[ks], bh0, s0, 0,0,0);
      s1 = __builtin_amdgcn_mfma_f32_16x16x32_bf16(qh[ks], bh1, s1, 0,0,0);
      s0 = __builtin_amdgcn_mfma_f32_16x16x32_bf16(ql[ks], bh0, s0, 0,0,0);
      s1 = __builtin_amdgcn_mfma_f32_16x16x32_bf16(ql[ks], bh1, s1, 0,0,0);
      s0 = __builtin_amdgcn_mfma_f32_16x16x32_bf16(qh[ks], bl0, s0, 0,0,0);
      s1 = __builtin_amdgcn_mfma_f32_16x16x32_bf16(qh[ks], bl1, s1, 0,0,0);
    }

    // ---- online softmax (row r lives in lanes with same g; reduce over 16 col-lanes)
    float scl[4];
    #pragma unroll
    for (int r = 0; r < 4; ++r){
      float v = fmaxf(s0[r], s1[r]);
      v = fmaxf(v, __shfl_xor(v, 1)); v = fmaxf(v, __shfl_xor(v, 2));
      v = fmaxf(v, __shfl_xor(v, 4)); v = fmaxf(v, __shfl_xor(v, 8));
      float mo = m_run[r];
      float mn = fmaxf(mo, v);
      m_run[r] = mn;
      float sc = __expf(mo - mn);                 // 0 on first tile (mo = -inf)
      scl[r] = sc;
      float p0 = __expf(s0[r] - mn);
      float p1 = __expf(s1[r] - mn);
      float ps = p0 + p1;
      ps += __shfl_xor(ps, 1); ps += __shfl_xor(ps, 2);
      ps += __shfl_xor(ps, 4); ps += __shfl_xor(ps, 8);
      l_run[r] = l_run[r]*sc + ps;
      int q = 16*wid + 4*g + r;                   // write P (wave-private rows)
      int pb = q*64;
      *(short*)(smem + SM_P + pb + (( 2*c      ) ^ (r<<4))) = (short)f2bf(p0);
      *(short*)(smem + SM_P + pb + ((32 + 2*c  ) ^ (r<<4))) = (short)f2bf(p1);
    }
    #pragma unroll
    for (int dt = 0; dt < 16; ++dt){
      o[dt][0] *= scl[0]; o[dt][1] *= scl[1]; o[dt][2] *= scl[2]; o[dt][3] *= scl[3];
    }

    // ---- PV: O += P·V   (A = P from LDS, B = V^T tile, 16 d-tiles)
    {
      int q = 16*wid + c;
      s16x8 pa = *(const s16x8*)(smem + SM_P + q*64 + ((16*g) ^ ((q&3)<<4)));
      #pragma unroll
      for (int dt = 0; dt < 16; ++dt){
        int vrow = 16*dt + c;
        s16x8 vb = *(const s16x8*)(smem + SM_VT + vrow*64 + ((16*g) ^ (((vrow>>2)&3)<<4)));
        o[dt] = __builtin_amdgcn_mfma_f32_16x16x32_bf16(pa, vb, o[dt], 0,0,0);
      }
    }
  }

  // ---- normalize O, park as bf16 in LDS (wave-private rows; overwrites K region)
  __syncthreads();
  {
    float inv[4];
    #pragma unroll
    for (int r = 0; r < 4; ++r) inv[r] = 1.0f / l_run[r];
    #pragma unroll
    for (int dt = 0; dt < 16; ++dt){
      #pragma unroll
      for (int r = 0; r < 4; ++r){
        int q = 16*wid + 4*g + r;
        int dcol = 16*dt + c;
        float val = o[dt][r] * inv[r];
        *(short*)(smem + SM_O + q*512 + ((2*dcol) ^ ((q&7)<<4))) = (short)f2bf(val);
      }
    }
  }

  // ---- FC: out = relu(concat(q, o, q-o, q*o) · W^T + b), W staged 128-f chunks
  f32x4 fa[8];
  #pragma unroll
  for (int i = 0; i < 8; ++i) fa[i] = (f32x4){0.f,0.f,0.f,0.f};

  #pragma unroll
  for (int fc = 0; fc < 8; ++fc){
    __syncthreads();
    #pragma unroll
    for (int p = 0; p < 8; ++p){                   // stage W[:,fc*128 .. +128) as bf16
      int h  = p*16 + (tid >> 4);
      int fl = (tid & 15) * 8;
      const float* srcw = Wm + (size_t)h*1024 + fc*128 + fl;
      float4 x0 = *(const float4*)srcw;
      float4 x1 = *(const float4*)(srcw + 4);
      s16x8 w8;
      w8[0]=(short)f2bf(x0.x); w8[1]=(short)f2bf(x0.y); w8[2]=(short)f2bf(x0.z); w8[3]=(short)f2bf(x0.w);
      w8[4]=(short)f2bf(x1.x); w8[5]=(short)f2bf(x1.y); w8[6]=(short)f2bf(x1.z); w8[7]=(short)f2bf(x1.w);
      *(s16x8*)(smem + SM_W + h*256 + ((2*fl) ^ ((h&7)<<4))) = w8;
    }
    __syncthreads();
    #pragma unroll
    for (int ks = 0; ks < 4; ++ks){
      const int cidx = (fc & 1)*4 + ks;            // global d-chunk (compile-time)
      s16x8 a;
      if (fc < 2){
        a = qh[cidx];                              // feature block 0: q
      } else {
        int q = 16*wid + c;
        s16x8 o8 = *(const s16x8*)(smem + SM_O + q*512 + ((64*cidx + 16*g) ^ ((q&7)<<4)));
        if (fc < 4){ a = o8; }                     // block 1: o
        else {
          #pragma unroll
          for (int j = 0; j < 8; ++j){             // block 2: q-o, block 3: q*o
            float qf = bf2f((unsigned short)qh[cidx][j]) + bf2f((unsigned short)ql[cidx][j]);
            float of = bf2f((unsigned short)o8[j]);
            float fv = (fc < 6) ? (qf - of) : (qf * of);
            a[j] = (short)f2bf(fv);
          }
        }
      }
      #pragma unroll
      for (int nt = 0; nt < 8; ++nt){
        int hh = 16*nt + c;
        s16x8 wb = *(const s16x8*)(smem + SM_W + hh*256 + ((64*ks + 16*g) ^ ((hh&7)<<4)));
        fa[nt] = __builtin_amdgcn_mfma_f32_16x16x32_bf16(a, wb, fa[nt], 0,0,0);
      }
    }
  }

  // ---- epilogue: bias + relu + coalesced store
  #pragma unroll
  for (int nt = 0; nt < 8; ++nt){
    float bs = bia[16*nt + c];
    #pragma unroll
    for (int r = 0; r < 4; ++r){
      int q = 16*wid + 4*g + r;
      float v = fa[nt][r] + bs;
      v = fmaxf(v, 0.f);
      outp[(size_t)q*NH + 16*nt + c] = v;
    }
  }
}

extern "C" void kernel_launch(void* const* d_in, const int* in_sizes, int n_in,
                              void* d_out, int out_size, void* d_ws, size_t ws_size,
                              hipStream_t stream) {
  (void)in_sizes; (void)n_in; (void)out_size; (void)d_ws; (void)ws_size;
  const float* cs = (const float*)d_in[0];
  const float* rs = (const float*)d_in[1];
  const float* W1 = (const float*)d_in[2];
  const float* b1 = (const float*)d_in[3];
  const float* W2 = (const float*)d_in[4];
  const float* b2 = (const float*)d_in[5];
  float* out = (float*)d_out;
  hipLaunchKernelGGL(lm_kernel, dim3(1280), dim3(256), 0, stream,
                     cs, rs, W1, b1, W2, b2, out);
}

// Round 2
// 613.928 us; speedup vs baseline: 1.2665x; 1.2665x over previous
//
#include <hip/hip_runtime.h>

// LocalMatching fused kernel for MI355X (gfx950) — round 2.
// Prep pass converts fp32 -> bf16 hi/lo into d_ws with pre-swizzled, tile-major
// layouts (incl. pre-transposed V with k-slot interleave). Main kernel stages
// tiles with global_load_lds (width 16), QK^T in bf16x3, PV + FC in bf16 MFMA.

#define NB  32
#define NLC 2048
#define NLR 512
#define ND  256
#define NH  128

typedef float f32x4 __attribute__((ext_vector_type(4)));
typedef short s16x8 __attribute__((ext_vector_type(8)));
typedef short s16x4 __attribute__((ext_vector_type(4)));

// ---- workspace layout (bytes) ----
// csh/csl: [b][t=64][kv=32][512B]   rows swizzled: byte(2d) ^ ((kv&7)<<4)
// rsh/rsl: [b][t=16][kv=32][512B]
// rshT/cshT: [b][t][d=256][64B]     slot s at (2s)^(((d>>2)&3)<<4), val=hi(V[pi(s)][d])
//                                   pi(s) = (s>>1) + 16*(s&1)
// Wh: [2][128][1024] bf16 plain row-major
#define WS_CSH 0ull
#define WS_CSL (WS_CSH + 33554432ull)
#define WS_RSH (WS_CSL + 33554432ull)
#define WS_RSL (WS_RSH + 8388608ull)
#define WS_RST (WS_RSL + 8388608ull)
#define WS_CST (WS_RST + 8388608ull)
#define WS_WH  (WS_CST + 33554432ull)
#define WS_NEED (WS_WH + 524288ull)

// ---- main-kernel LDS layout (52 KiB) ----
#define SM_KH 0
#define SM_KL 16384
#define SM_VT 32768
#define SM_P  49152
#define SM_O  0          // FC phase, after barrier

__device__ __forceinline__ unsigned short f2bf(float x){
  unsigned u = __builtin_bit_cast(unsigned, x);
  u += 0x7FFFu + ((u >> 16) & 1u);
  return (unsigned short)(u >> 16);
}
__device__ __forceinline__ float bf2f(unsigned short h){
  unsigned u = ((unsigned)h) << 16;
  return __builtin_bit_cast(float, u);
}
__device__ __forceinline__ void splitbf(float x, short &hi, short &lo){
  unsigned short h = f2bf(x);
  float r = x - bf2f(h);
  hi = (short)h;
  lo = (short)f2bf(r);
}
__device__ __forceinline__ void gll16(const void* g, void* l){
  __builtin_amdgcn_global_load_lds((const __attribute__((address_space(1))) void*)g,
                                   (__attribute__((address_space(3))) void*)l, 16, 0, 0);
}

// ================= prep kernels =================

__global__ __launch_bounds__(256)
void prep_rows(const float* __restrict__ cs, const float* __restrict__ rs,
               const float* __restrict__ W1, const float* __restrict__ W2,
               unsigned char* __restrict__ ws)
{
  const int tid = threadIdx.x, lane = tid & 63, wid = tid >> 6;
  const int bid = blockIdx.x;
  if (bid < 20480){
    const float* srcrow; unsigned char *dsth, *dstl; int kvl;
    if (bid < 16384){
      int row = bid*4 + wid;                       // b*2048 + pos
      int b = row >> 11, pos = row & 2047, t = pos >> 5; kvl = pos & 31;
      srcrow = cs + (size_t)row*ND;
      size_t off = ((size_t)(b*64 + t)*32 + kvl)*512;
      dsth = ws + WS_CSH + off; dstl = ws + WS_CSL + off;
    } else {
      int row = (bid - 16384)*4 + wid;             // b*512 + pos
      int b = row >> 9, pos = row & 511, t = pos >> 5; kvl = pos & 31;
      srcrow = rs + (size_t)row*ND;
      size_t off = ((size_t)(b*16 + t)*32 + kvl)*512;
      dsth = ws + WS_RSH + off; dstl = ws + WS_RSL + off;
    }
    float4 x = *((const float4*)srcrow + lane);
    short h0,l0,h1,l1,h2,l2,h3,l3;
    splitbf(x.x,h0,l0); splitbf(x.y,h1,l1); splitbf(x.z,h2,l2); splitbf(x.w,h3,l3);
    int boff = (8*lane) ^ ((kvl & 7) << 4);
    *(s16x4*)(dsth + boff) = (s16x4){h0,h1,h2,h3};
    *(s16x4*)(dstl + boff) = (s16x4){l0,l1,l2,l3};
  } else {
    int idx = (bid - 20480)*2048 + tid*8;          // 0 .. 262143
    const float* srcw = (idx < 131072) ? (W1 + idx) : (W2 + (idx - 131072));
    float4 a = *(const float4*)srcw;
    float4 c4 = *((const float4*)srcw + 1);
    s16x8 h;
    h[0]=(short)f2bf(a.x); h[1]=(short)f2bf(a.y); h[2]=(short)f2bf(a.z); h[3]=(short)f2bf(a.w);
    h[4]=(short)f2bf(c4.x); h[5]=(short)f2bf(c4.y); h[6]=(short)f2bf(c4.z); h[7]=(short)f2bf(c4.w);
    *(s16x8*)(ws + WS_WH + (size_t)idx*2) = h;
  }
}

__global__ __launch_bounds__(256)
void prep_T(const float* __restrict__ cs, const float* __restrict__ rs,
            unsigned char* __restrict__ ws)
{
  __shared__ float tile[32][256];
  const int tid = threadIdx.x, lane = tid & 63, wid = tid >> 6;
  const int bid = blockIdx.x;
  const float* src; unsigned char* dst;
  if (bid < 512){ int b = bid >> 4, t = bid & 15;
    src = rs + ((size_t)b*NLR + t*32)*ND;
    dst = ws + WS_RST + (size_t)bid*16384;
  } else { int b2 = bid - 512; int b = b2 >> 6, t = b2 & 63;
    src = cs + ((size_t)b*NLC + t*32)*ND;
    dst = ws + WS_CST + (size_t)b2*16384;
  }
  #pragma unroll
  for (int i = 0; i < 8; ++i){
    int r = wid*8 + i;
    float4 x = *((const float4*)(src + (size_t)r*ND) + lane);
    *(float4*)&tile[r][lane*4] = x;
  }
  __syncthreads();
  const int d = tid;
  const int swzc = (d >> 2) & 3;
  unsigned char* orow = dst + d*64;
  #pragma unroll
  for (int ci = 0; ci < 4; ++ci){
    int sg = ci ^ swzc;
    s16x8 w;
    #pragma unroll
    for (int j = 0; j < 8; ++j){
      int kvl = 4*sg + (j >> 1) + ((j & 1) << 4);  // pi(8*sg+j)
      w[j] = (short)f2bf(tile[kvl][d]);
    }
    *(s16x8*)(orow + 16*ci) = w;
  }
}

// ================= main kernel =================

__global__ __launch_bounds__(256, 3)
void lm_main(const unsigned char* __restrict__ ws,
             const float* __restrict__ b1, const float* __restrict__ b2,
             float* __restrict__ out)
{
  __shared__ __align__(16) char smem[53248];

  const int tid  = threadIdx.x;
  const int lane = tid & 63;
  const int wid  = tid >> 6;
  const int c    = lane & 15;
  const int g    = lane >> 4;

  int bid = blockIdx.x;
  int dir, b, qt;
  if (bid < 256){ dir = 1; int xcd = bid & 7, inner = bid >> 3;
    b = xcd*4 + (inner >> 3); qt = inner & 7; }
  else { dir = 0; int t2 = bid - 256; int xcd = t2 & 7, inner = t2 >> 3;
    b = xcd*4 + (inner >> 5); qt = inner & 31; }

  const unsigned char *QH, *QL, *KH, *KL, *VT;
  int NT;
  if (dir == 0){
    QH = ws + WS_CSH + (size_t)b*64*16384;  QL = ws + WS_CSL + (size_t)b*64*16384;
    KH = ws + WS_RSH + (size_t)b*16*16384;  KL = ws + WS_RSL + (size_t)b*16*16384;
    VT = ws + WS_RST + (size_t)b*16*16384;  NT = 16;
  } else {
    QH = ws + WS_RSH + (size_t)b*16*16384;  QL = ws + WS_RSL + (size_t)b*16*16384;
    KH = ws + WS_CSH + (size_t)b*64*16384;  KL = ws + WS_CSL + (size_t)b*64*16384;
    VT = ws + WS_CST + (size_t)b*64*16384;  NT = 64;
  }
  const unsigned char* Wp = ws + WS_WH + (size_t)dir*262144;
  const float* bia = dir ? b2 : b1;
  float* outp = dir == 0 ? out + ((size_t)b*NLC + qt*64)*NH
                         : out + (size_t)NB*NLC*NH + ((size_t)b*NLR + qt*64)*NH;

  // ---- Q fragments from pre-swizzled ws (held in registers all kernel)
  s16x8 qh[8], ql[8];
  {
    int q = qt*64 + 16*wid + c;
    const unsigned char* qrowH = QH + (size_t)(q >> 5)*16384 + (size_t)(q & 31)*512;
    const unsigned char* qrowL = QL + (size_t)(q >> 5)*16384 + (size_t)(q & 31)*512;
    int qx = (q & 7) << 4;
    #pragma unroll
    for (int ks = 0; ks < 8; ++ks){
      int off = (64*ks + 16*g) ^ qx;
      qh[ks] = *(const s16x8*)(qrowH + off);
      ql[ks] = *(const s16x8*)(qrowL + off);
    }
  }

  f32x4 o[16];
  #pragma unroll
  for (int i = 0; i < 16; ++i) o[i] = (f32x4){0.f,0.f,0.f,0.f};
  float m_run[4] = {-INFINITY,-INFINITY,-INFINITY,-INFINITY};
  float l_run[4] = {0.f,0.f,0.f,0.f};

  for (int t = 0; t < NT; ++t){
    __syncthreads();
    // ---- stage tile: 48 x global_load_lds (16B/lane), zero VALU, linear dest
    {
      const unsigned char* kh = KH + (size_t)t*16384;
      const unsigned char* kl = KL + (size_t)t*16384;
      const unsigned char* vt = VT + (size_t)t*16384;
      #pragma unroll
      for (int i = 0; i < 12; ++i){
        int j = 4*i + wid;
        const unsigned char* src; int dst;
        if (j < 16){ src = kh + (size_t)j*1024;        dst = SM_KH + j*1024; }
        else if (j < 32){ src = kl + (size_t)(j-16)*1024; dst = SM_KL + (j-16)*1024; }
        else { src = vt + (size_t)(j-32)*1024;          dst = SM_VT + (j-32)*1024; }
        gll16(src + (size_t)lane*16, smem + dst);
      }
    }
    __syncthreads();

    // ---- S = Q.K^T (bf16x3)
    f32x4 s0 = (f32x4){0.f,0.f,0.f,0.f}, s1 = (f32x4){0.f,0.f,0.f,0.f};
    #pragma unroll
    for (int ks = 0; ks < 8; ++ks){
      int kb = 64*ks + 16*g;
      int o0 = c*512 + (kb ^ ((c & 7) << 4));
      int o1 = (16 + c)*512 + (kb ^ (((16 + c) & 7) << 4));
      s16x8 bh0 = *(const s16x8*)(smem + SM_KH + o0);
      s16x8 bl0 = *(const s16x8*)(smem + SM_KL + o0);
      s16x8 bh1 = *(const s16x8*)(smem + SM_KH + o1);
      s16x8 bl1 = *(const s16x8*)(smem + SM_KL + o1);
      s0 = __builtin_amdgcn_mfma_f32_16x16x32_bf16(qh[ks], bh0, s0, 0,0,0);
      s1 = __builtin_amdgcn_mfma_f32_16x16x32_bf16(qh[ks], bh1, s1, 0,0,0);
      s0 = __builtin_amdgcn_mfma_f32_16x16x32_bf16(ql[ks], bh0, s0, 0,0,0);
      s1 = __builtin_amdgcn_mfma_f32_16x16x32_bf16(ql[ks], bh1, s1, 0,0,0);
      s0 = __builtin_amdgcn_mfma_f32_16x16x32_bf16(qh[ks], bl0, s0, 0,0,0);
      s1 = __builtin_amdgcn_mfma_f32_16x16x32_bf16(qh[ks], bl1, s1, 0,0,0);
    }

    // ---- online softmax; P written as one packed b32 per lane per r
    float scl[4];
    #pragma unroll
    for (int r = 0; r < 4; ++r){
      float v = fmaxf(s0[r], s1[r]);
      v = fmaxf(v, __shfl_xor(v, 1)); v = fmaxf(v, __shfl_xor(v, 2));
      v = fmaxf(v, __shfl_xor(v, 4)); v = fmaxf(v, __shfl_xor(v, 8));
      float mo = m_run[r];
      float mn = fmaxf(mo, v);
      m_run[r] = mn;
      float sc = __expf(mo - mn);
      scl[r] = sc;
      float p0 = __expf(s0[r] - mn);
      float p1 = __expf(s1[r] - mn);
      float ps = p0 + p1;
      ps += __shfl_xor(ps, 1); ps += __shfl_xor(ps, 2);
      ps += __shfl_xor(ps, 4); ps += __shfl_xor(ps, 8);
      l_run[r] = l_run[r]*sc + ps;
      int qr = 16*wid + 4*g + r;
      unsigned pk = (unsigned)f2bf(p0) | ((unsigned)f2bf(p1) << 16);
      *(unsigned*)(smem + SM_P + qr*64 + ((4*c) ^ (r << 4))) = pk;
    }
    #pragma unroll
    for (int dt = 0; dt < 16; ++dt){
      o[dt][0] *= scl[0]; o[dt][1] *= scl[1]; o[dt][2] *= scl[2]; o[dt][3] *= scl[3];
    }

    // ---- PV (k-slot-interleaved layouts on both A and B)
    {
      int q2 = 16*wid + c;
      s16x8 pa = *(const s16x8*)(smem + SM_P + q2*64 + ((16*g) ^ ((q2 & 3) << 4)));
      #pragma unroll
      for (int dt = 0; dt < 16; ++dt){
        int vrow = 16*dt + c;
        s16x8 vb = *(const s16x8*)(smem + SM_VT + vrow*64 + ((16*g) ^ (((vrow >> 2) & 3) << 4)));
        o[dt] = __builtin_amdgcn_mfma_f32_16x16x32_bf16(pa, vb, o[dt], 0,0,0);
      }
    }
  }

  // ---- normalize O, park bf16 in LDS
  __syncthreads();
  {
    float inv[4];
    #pragma unroll
    for (int r = 0; r < 4; ++r) inv[r] = 1.0f / l_run[r];
    #pragma unroll
    for (int dt = 0; dt < 16; ++dt){
      #pragma unroll
      for (int r = 0; r < 4; ++r){
        int qr = 16*wid + 4*g + r;
        int dcol = 16*dt + c;
        float val = o[dt][r] * inv[r];
        *(short*)(smem + SM_O + qr*512 + ((2*dcol) ^ ((qr & 7) << 4))) = (short)f2bf(val);
      }
    }
  }
  __syncthreads();

  // ---- FC: W read directly from L2-hot bf16 ws copy (no LDS staging, no barriers)
  f32x4 fa[8];
  #pragma unroll
  for (int i = 0; i < 8; ++i) fa[i] = (f32x4){0.f,0.f,0.f,0.f};

  #pragma unroll
  for (int fc = 0; fc < 8; ++fc){
    #pragma unroll
    for (int ksl = 0; ksl < 4; ++ksl){
      const int cidx = (fc & 1)*4 + ksl;
      s16x8 a;
      if (fc < 2){
        a = qh[cidx];
      } else {
        int q2 = 16*wid + c;
        s16x8 o8 = *(const s16x8*)(smem + SM_O + q2*512 + ((64*cidx + 16*g) ^ ((q2 & 7) << 4)));
        if (fc < 4){ a = o8; }
        else {
          #pragma unroll
          for (int j = 0; j < 8; ++j){
            float qf = bf2f((unsigned short)qh[cidx][j]) + bf2f((unsigned short)ql[cidx][j]);
            float of = bf2f((unsigned short)o8[j]);
            float fv = (fc < 6) ? (qf - of) : (qf * of);
            a[j] = (short)f2bf(fv);
          }
        }
      }
      #pragma unroll
      for (int nt = 0; nt < 8; ++nt){
        s16x8 wb = *(const s16x8*)(Wp + (size_t)(16*nt + c)*2048 + 2*(fc*128 + 32*ksl + 8*g));
        fa[nt] = __builtin_amdgcn_mfma_f32_16x16x32_bf16(a, wb, fa[nt], 0,0,0);
      }
    }
  }

  #pragma unroll
  for (int nt = 0; nt < 8; ++nt){
    float bs = bia[16*nt + c];
    #pragma unroll
    for (int r = 0; r < 4; ++r){
      int qr = 16*wid + 4*g + r;
      float v = fa[nt][r] + bs;
      v = fmaxf(v, 0.f);
      outp[(size_t)qr*NH + 16*nt + c] = v;
    }
  }
}

// ================= fallback (round-1 kernel, used if ws too small) =================

__global__ __launch_bounds__(256, 2)
void lm_fallback(const float* __restrict__ cs, const float* __restrict__ rs,
                 const float* __restrict__ W1, const float* __restrict__ b1,
                 const float* __restrict__ W2, const float* __restrict__ b2,
                 float* __restrict__ out)
{
  __shared__ __align__(16) char smem[65536];
  const int tid  = threadIdx.x;
  const int lane = tid & 63;
  const int wid  = tid >> 6;
  const int c    = lane & 15;
  const int g    = lane >> 4;

  int bid = blockIdx.x;
  int dir, b, qt;
  if (bid < 1024){ int xcd = bid & 7, inner = bid >> 3;
    b = (xcd << 2) + (inner >> 5); qt = inner & 31; dir = 0; }
  else { int t2 = bid - 1024; int xcd = t2 & 7, inner = t2 >> 3;
    b = (xcd << 2) + (inner >> 3); qt = inner & 7; dir = 1; }

  const float* Q   = dir == 0 ? cs + ((size_t)b*NLC + qt*64)*ND
                              : rs + ((size_t)b*NLR + qt*64)*ND;
  const float* KV  = dir == 0 ? rs + (size_t)b*NLR*ND : cs + (size_t)b*NLC*ND;
  const int    NK  = dir == 0 ? NLR : NLC;
  const float* Wm  = dir == 0 ? W1 : W2;
  const float* bia = dir == 0 ? b1 : b2;
  float* outp = dir == 0 ? out + ((size_t)b*NLC + qt*64)*NH
                         : out + (size_t)NB*NLC*NH + ((size_t)b*NLR + qt*64)*NH;

  s16x8 qh[8], ql[8];
  {
    const float* qrow = Q + (size_t)(16*wid + c)*ND;
    #pragma unroll
    for (int ks = 0; ks < 8; ++ks){
      float4 x0 = *(const float4*)(qrow + 32*ks + 8*g);
      float4 x1 = *(const float4*)(qrow + 32*ks + 8*g + 4);
      float xs[8] = {x0.x,x0.y,x0.z,x0.w,x1.x,x1.y,x1.z,x1.w};
      #pragma unroll
      for (int j = 0; j < 8; ++j){ short h,l; splitbf(xs[j],h,l); qh[ks][j]=h; ql[ks][j]=l; }
    }
  }

  f32x4 o[16];
  #pragma unroll
  for (int i = 0; i < 16; ++i) o[i] = (f32x4){0.f,0.f,0.f,0.f};
  float m_run[4] = {-INFINITY,-INFINITY,-INFINITY,-INFINITY};
  float l_run[4] = {0.f,0.f,0.f,0.f};

  const int ntile = NK >> 5;
  for (int t = 0; t < ntile; ++t){
    __syncthreads();
    {
      const float* KVt = KV + (size_t)t*32*ND;
      #pragma unroll
      for (int p = 0; p < 8; ++p){
        int kvloc = p*4 + wid;
        float4 x = *((const float4*)(KVt + kvloc*ND) + lane);
        short h0,l0,h1,l1,h2,l2,h3,l3;
        splitbf(x.x,h0,l0); splitbf(x.y,h1,l1); splitbf(x.z,h2,l2); splitbf(x.w,h3,l3);
        int roff = kvloc*512 + ((8*lane) ^ ((kvloc&7)<<4));
        *(s16x4*)(smem + 0     + roff) = (s16x4){h0,h1,h2,h3};
        *(s16x4*)(smem + 16384 + roff) = (s16x4){l0,l1,l2,l3};
        int d0 = 4*lane;
        short hs[4] = {h0,h1,h2,h3};
        #pragma unroll
        for (int j = 0; j < 4; ++j){
          int dr = d0 + j;
          int voff = dr*64 + ((2*kvloc) ^ (((dr>>2)&3)<<4));
          *(short*)(smem + 32768 + voff) = hs[j];
        }
      }
    }
    __syncthreads();

    f32x4 s0 = (f32x4){0.f,0.f,0.f,0.f}, s1 = (f32x4){0.f,0.f,0.f,0.f};
    #pragma unroll
    for (int ks = 0; ks < 8; ++ks){
      int kb = 64*ks + 16*g;
      int o0 = c*512 + (kb ^ ((c&7)<<4));
      int o1 = (16+c)*512 + (kb ^ (((16+c)&7)<<4));
      s16x8 bh0 = *(const s16x8*)(smem + 0     + o0);
      s16x8 bl0 = *(const s16x8*)(smem + 16384 + o0);
      s16x8 bh1 = *(const s16x8*)(smem + 0     + o1);
      s16x8 bl1 = *(const s16x8*)(smem + 16384 + o1);
      s0 = __builtin_amdgcn_mfma_f32_16x16x32_bf16(qh[ks], bh0, s0, 0,0,0);
      s1 = __builtin_amdgcn_mfma_f32_16x16x32_bf16(qh[ks], bh1, s1, 0,0,0);
      s0 = __builtin_amdgcn_mfma_f32_16x16x32_bf16(ql[ks], bh0, s0, 0,0,0);
      s1 = __builtin_amdgcn_mfma_f32_16x16x32_bf16(ql[ks], bh1, s1, 0,0,0);
      s0 = __builtin_amdgcn_mfma_f32_16x16x32_bf16(qh[ks], bl0, s0, 0,0,0);
      s1 = __builtin_amdgcn_mfma_f32_16x16x32_bf16(qh[ks], bl1, s1, 0,0,0);
    }

    float scl[4];
    #pragma unroll
    for (int r = 0; r < 4; ++r){
      float v = fmaxf(s0[r], s1[r]);
      v = fmaxf(v, __shfl_xor(v, 1)); v = fmaxf(v, __shfl_xor(v, 2));
      v = fmaxf(v, __shfl_xor(v, 4)); v = fmaxf(v, __shfl_xor(v, 8));
      float mo = m_run[r];
      float mn = fmaxf(mo, v);
      m_run[r] = mn;
      float sc = __expf(mo - mn);
      scl[r] = sc;
      float p0 = __expf(s0[r] - mn);
      float p1 = __expf(s1[r] - mn);
      float ps = p0 + p1;
      ps += __shfl_xor(ps, 1); ps += __shfl_xor(ps, 2);
      ps += __shfl_xor(ps, 4); ps += __shfl_xor(ps, 8);
      l_run[r] = l_run[r]*sc + ps;
      int q = 16*wid + 4*g + r;
      int pb = q*64;
      *(short*)(smem + 49152 + pb + (( 2*c     ) ^ (r<<4))) = (short)f2bf(p0);
      *(short*)(smem + 49152 + pb + ((32 + 2*c ) ^ (r<<4))) = (short)f2bf(p1);
    }
    #pragma unroll
    for (int dt = 0; dt < 16; ++dt){
      o[dt][0] *= scl[0]; o[dt][1] *= scl[1]; o[dt][2] *= scl[2]; o[dt][3] *= scl[3];
    }

    {
      int q = 16*wid + c;
      s16x8 pa = *(const s16x8*)(smem + 49152 + q*64 + ((16*g) ^ ((q&3)<<4)));
      #pragma unroll
      for (int dt = 0; dt < 16; ++dt){
        int vrow = 16*dt + c;
        s16x8 vb = *(const s16x8*)(smem + 32768 + vrow*64 + ((16*g) ^ (((vrow>>2)&3)<<4)));
        o[dt] = __builtin_amdgcn_mfma_f32_16x16x32_bf16(pa, vb, o[dt], 0,0,0);
      }
    }
  }

  __syncthreads();
  {
    float inv[4];
    #pragma unroll
    for (int r = 0; r < 4; ++r) inv[r] = 1.0f / l_run[r];
    #pragma unroll
    for (int dt = 0; dt < 16; ++dt){
      #pragma unroll
      for (int r = 0; r < 4; ++r){
        int q = 16*wid + 4*g + r;
        int dcol = 16*dt + c;
        float val = o[dt][r] * inv[r];
        *(short*)(smem + 0 + q*512 + ((2*dcol) ^ ((q&7)<<4))) = (short)f2bf(val);
      }
    }
  }

  f32x4 fa[8];
  #pragma unroll
  for (int i = 0; i < 8; ++i) fa[i] = (f32x4){0.f,0.f,0.f,0.f};

  #pragma unroll
  for (int fc = 0; fc < 8; ++fc){
    __syncthreads();
    #pragma unroll
    for (int p = 0; p < 8; ++p){
      int h  = p*16 + (tid >> 4);
      int fl = (tid & 15) * 8;
      const float* srcw = Wm + (size_t)h*1024 + fc*128 + fl;
      float4 x0 = *(const float4*)srcw;
      float4 x1 = *(const float4*)(srcw + 4);
      s16x8 w8;
      w8[0]=(short)f2bf(x0.x); w8[1]=(short)f2bf(x0.y); w8[2]=(short)f2bf(x0.z); w8[3]=(short)f2bf(x0.w);
      w8[4]=(short)f2bf(x1.x); w8[5]=(short)f2bf(x1.y); w8[6]=(short)f2bf(x1.z); w8[7]=(short)f2bf(x1.w);
      *(s16x8*)(smem + 32768 + h*256 + ((2*fl) ^ ((h&7)<<4))) = w8;
    }
    __syncthreads();
    #pragma unroll
    for (int ks = 0; ks < 4; ++ks){
      const int cidx = (fc & 1)*4 + ks;
      s16x8 a;
      if (fc < 2){
        a = qh[cidx];
      } else {
        int q = 16*wid + c;
        s16x8 o8 = *(const s16x8*)(smem + 0 + q*512 + ((64*cidx + 16*g) ^ ((q&7)<<4)));
        if (fc < 4){ a = o8; }
        else {
          #pragma unroll
          for (int j = 0; j < 8; ++j){
            float qf = bf2f((unsigned short)qh[cidx][j]) + bf2f((unsigned short)ql[cidx][j]);
            float of = bf2f((unsigned short)o8[j]);
            float fv = (fc < 6) ? (qf - of) : (qf * of);
            a[j] = (short)f2bf(fv);
          }
        }
      }
      #pragma unroll
      for (int nt = 0; nt < 8; ++nt){
        int hh = 16*nt + c;
        s16x8 wb = *(const s16x8*)(smem + 32768 + hh*256 + ((64*ks + 16*g) ^ ((hh&7)<<4)));
        fa[nt] = __builtin_amdgcn_mfma_f32_16x16x32_bf16(a, wb, fa[nt], 0,0,0);
      }
    }
  }

  #pragma unroll
  for (int nt = 0; nt < 8; ++nt){
    float bs = bia[16*nt + c];
    #pragma unroll
    for (int r = 0; r < 4; ++r){
      int q = 16*wid + 4*g + r;
      float v = fa[nt][r] + bs;
      v = fmaxf(v, 0.f);
      outp[(size_t)q*NH + 16*nt + c] = v;
    }
  }
}

extern "C" void kernel_launch(void* const* d_in, const int* in_sizes, int n_in,
                              void* d_out, int out_size, void* d_ws, size_t ws_size,
                              hipStream_t stream) {
  (void)in_sizes; (void)n_in; (void)out_size;
  const float* cs = (const float*)d_in[0];
  const float* rs = (const float*)d_in[1];
  const float* W1 = (const float*)d_in[2];
  const float* b1 = (const float*)d_in[3];
  const float* W2 = (const float*)d_in[4];
  const float* b2 = (const float*)d_in[5];
  float* out = (float*)d_out;

  if (ws_size >= WS_NEED){
    unsigned char* ws = (unsigned char*)d_ws;
    hipLaunchKernelGGL(prep_rows, dim3(20608), dim3(256), 0, stream, cs, rs, W1, W2, ws);
    hipLaunchKernelGGL(prep_T,    dim3(2560),  dim3(256), 0, stream, cs, rs, ws);
    hipLaunchKernelGGL(lm_main,   dim3(1280),  dim3(256), 0, stream, ws, b1, b2, out);
  } else {
    hipLaunchKernelGGL(lm_fallback, dim3(1280), dim3(256), 0, stream,
                       cs, rs, W1, b1, W2, b2, out);
  }
}

// Round 4
// 484.314 us; speedup vs baseline: 1.6055x; 1.2676x over previous
//
#include <hip/hip_runtime.h>

// LocalMatching fused kernel for MI355X (gfx950) — round 3 (resubmit, r3 bench
// never acquired a GPU). Round-2 + T3-lite pipeline: double-buffered KV tiles,
// next-tile global_load_lds issued BEFORE current-tile compute, ONE barrier per
// tile. 8 waves / QBLK=128, dir1 (heavy) blocks first. Layouts identical to r2.

#define NB  32
#define NLC 2048
#define NLR 512
#define ND  256
#define NH  128

typedef float f32x4 __attribute__((ext_vector_type(4)));
typedef short s16x8 __attribute__((ext_vector_type(8)));
typedef short s16x4 __attribute__((ext_vector_type(4)));

// ---- workspace layout (bytes) ----
#define WS_CSH 0ull
#define WS_CSL (WS_CSH + 33554432ull)
#define WS_RSH (WS_CSL + 33554432ull)
#define WS_RSL (WS_RSH + 8388608ull)
#define WS_RST (WS_RSL + 8388608ull)
#define WS_CST (WS_RST + 8388608ull)
#define WS_WH  (WS_CST + 33554432ull)
#define WS_NEED (WS_WH + 524288ull)

// ---- main-kernel LDS: buf0 [0,48K) buf1 [48K,96K) P [96K,104K); FC: O at [0,64K)
#define BUFSZ 49152
#define SM_P  98304
#define SM_O  0

__device__ __forceinline__ unsigned short f2bf(float x){
  unsigned u = __builtin_bit_cast(unsigned, x);
  u += 0x7FFFu + ((u >> 16) & 1u);
  return (unsigned short)(u >> 16);
}
__device__ __forceinline__ float bf2f(unsigned short h){
  unsigned u = ((unsigned)h) << 16;
  return __builtin_bit_cast(float, u);
}
__device__ __forceinline__ void splitbf(float x, short &hi, short &lo){
  unsigned short h = f2bf(x);
  float r = x - bf2f(h);
  hi = (short)h;
  lo = (short)f2bf(r);
}
__device__ __forceinline__ void gll16(const void* g, void* l){
  __builtin_amdgcn_global_load_lds((const __attribute__((address_space(1))) void*)g,
                                   (__attribute__((address_space(3))) void*)l, 16, 0, 0);
}

// ================= prep kernels (unchanged from r2) =================

__global__ __launch_bounds__(256)
void prep_rows(const float* __restrict__ cs, const float* __restrict__ rs,
               const float* __restrict__ W1, const float* __restrict__ W2,
               unsigned char* __restrict__ ws)
{
  const int tid = threadIdx.x, lane = tid & 63, wid = tid >> 6;
  const int bid = blockIdx.x;
  if (bid < 20480){
    const float* srcrow; unsigned char *dsth, *dstl; int kvl;
    if (bid < 16384){
      int row = bid*4 + wid;
      int b = row >> 11, pos = row & 2047, t = pos >> 5; kvl = pos & 31;
      srcrow = cs + (size_t)row*ND;
      size_t off = ((size_t)(b*64 + t)*32 + kvl)*512;
      dsth = ws + WS_CSH + off; dstl = ws + WS_CSL + off;
    } else {
      int row = (bid - 16384)*4 + wid;
      int b = row >> 9, pos = row & 511, t = pos >> 5; kvl = pos & 31;
      srcrow = rs + (size_t)row*ND;
      size_t off = ((size_t)(b*16 + t)*32 + kvl)*512;
      dsth = ws + WS_RSH + off; dstl = ws + WS_RSL + off;
    }
    float4 x = *((const float4*)srcrow + lane);
    short h0,l0,h1,l1,h2,l2,h3,l3;
    splitbf(x.x,h0,l0); splitbf(x.y,h1,l1); splitbf(x.z,h2,l2); splitbf(x.w,h3,l3);
    int boff = (8*lane) ^ ((kvl & 7) << 4);
    *(s16x4*)(dsth + boff) = (s16x4){h0,h1,h2,h3};
    *(s16x4*)(dstl + boff) = (s16x4){l0,l1,l2,l3};
  } else {
    int idx = (bid - 20480)*2048 + tid*8;
    const float* srcw = (idx < 131072) ? (W1 + idx) : (W2 + (idx - 131072));
    float4 a = *(const float4*)srcw;
    float4 c4 = *((const float4*)srcw + 1);
    s16x8 h;
    h[0]=(short)f2bf(a.x); h[1]=(short)f2bf(a.y); h[2]=(short)f2bf(a.z); h[3]=(short)f2bf(a.w);
    h[4]=(short)f2bf(c4.x); h[5]=(short)f2bf(c4.y); h[6]=(short)f2bf(c4.z); h[7]=(short)f2bf(c4.w);
    *(s16x8*)(ws + WS_WH + (size_t)idx*2) = h;
  }
}

__global__ __launch_bounds__(256)
void prep_T(const float* __restrict__ cs, const float* __restrict__ rs,
            unsigned char* __restrict__ ws)
{
  __shared__ float tile[32][256];
  const int tid = threadIdx.x, lane = tid & 63, wid = tid >> 6;
  const int bid = blockIdx.x;
  const float* src; unsigned char* dst;
  if (bid < 512){ int b = bid >> 4, t = bid & 15;
    src = rs + ((size_t)b*NLR + t*32)*ND;
    dst = ws + WS_RST + (size_t)bid*16384;
  } else { int b2 = bid - 512; int b = b2 >> 6, t = b2 & 63;
    src = cs + ((size_t)b*NLC + t*32)*ND;
    dst = ws + WS_CST + (size_t)b2*16384;
  }
  #pragma unroll
  for (int i = 0; i < 8; ++i){
    int r = wid*8 + i;
    float4 x = *((const float4*)(src + (size_t)r*ND) + lane);
    *(float4*)&tile[r][lane*4] = x;
  }
  __syncthreads();
  const int d = tid;
  const int swzc = (d >> 2) & 3;
  unsigned char* orow = dst + d*64;
  #pragma unroll
  for (int ci = 0; ci < 4; ++ci){
    int sg = ci ^ swzc;
    s16x8 w;
    #pragma unroll
    for (int j = 0; j < 8; ++j){
      int kvl = 4*sg + (j >> 1) + ((j & 1) << 4);
      w[j] = (short)f2bf(tile[kvl][d]);
    }
    *(s16x8*)(orow + 16*ci) = w;
  }
}

// ================= main kernel =================

__global__ __launch_bounds__(512, 2)
void lm_main(const unsigned char* __restrict__ ws,
             const float* __restrict__ b1, const float* __restrict__ b2,
             float* __restrict__ out)
{
  __shared__ __align__(16) char smem[106496];

  const int tid  = threadIdx.x;
  const int lane = tid & 63;
  const int wid  = tid >> 6;        // 0..7, owns q rows [16*wid, 16*wid+16)
  const int c    = lane & 15;
  const int g    = lane >> 4;

  // dir1 (heavy, 64 tiles) first: bids [0,128); dir0: [128,640)
  int bid = blockIdx.x;
  int dir, b, qt;
  if (bid < 128){ dir = 1; int xcd = bid & 7, inner = bid >> 3;
    b = xcd*4 + (inner >> 2); qt = inner & 3; }
  else { dir = 0; int t2 = bid - 128; int xcd = t2 & 7, inner = t2 >> 3;
    b = xcd*4 + (inner >> 4); qt = inner & 15; }

  const unsigned char *QH, *QL, *KH, *KL, *VT;
  int NT;
  if (dir == 0){
    QH = ws + WS_CSH + (size_t)b*64*16384;  QL = ws + WS_CSL + (size_t)b*64*16384;
    KH = ws + WS_RSH + (size_t)b*16*16384;  KL = ws + WS_RSL + (size_t)b*16*16384;
    VT = ws + WS_RST + (size_t)b*16*16384;  NT = 16;
  } else {
    QH = ws + WS_RSH + (size_t)b*16*16384;  QL = ws + WS_RSL + (size_t)b*16*16384;
    KH = ws + WS_CSH + (size_t)b*64*16384;  KL = ws + WS_CSL + (size_t)b*64*16384;
    VT = ws + WS_CST + (size_t)b*64*16384;  NT = 64;
  }
  const unsigned char* Wp = ws + WS_WH + (size_t)dir*262144;
  const float* bia = dir ? b2 : b1;
  float* outp = dir == 0 ? out + ((size_t)b*NLC + qt*128)*NH
                         : out + (size_t)NB*NLC*NH + ((size_t)b*NLR + qt*128)*NH;

  // ---- Q fragments (hi/lo) held in registers all kernel
  s16x8 qh[8], ql[8];
  {
    int q = qt*128 + 16*wid + c;
    const unsigned char* qrowH = QH + (size_t)(q >> 5)*16384 + (size_t)(q & 31)*512;
    const unsigned char* qrowL = QL + (size_t)(q >> 5)*16384 + (size_t)(q & 31)*512;
    int qx = (q & 7) << 4;
    #pragma unroll
    for (int ks = 0; ks < 8; ++ks){
      int off = (64*ks + 16*g) ^ qx;
      qh[ks] = *(const s16x8*)(qrowH + off);
      ql[ks] = *(const s16x8*)(qrowL + off);
    }
  }

  f32x4 o[16];
  #pragma unroll
  for (int i = 0; i < 16; ++i) o[i] = (f32x4){0.f,0.f,0.f,0.f};
  float m_run[4] = {-INFINITY,-INFINITY,-INFINITY,-INFINITY};
  float l_run[4] = {0.f,0.f,0.f,0.f};

  // ---- stage helper: 48 gll16 per tile, 6 per wave, linear LDS dest
  #define STAGE(tt, bsel) do {                                              \
    const unsigned char* kh_ = KH + (size_t)(tt)*16384;                     \
    const unsigned char* kl_ = KL + (size_t)(tt)*16384;                     \
    const unsigned char* vt_ = VT + (size_t)(tt)*16384;                     \
    char* bb_ = smem + (bsel)*BUFSZ;                                        \
    _Pragma("unroll")                                                       \
    for (int i_ = 0; i_ < 6; ++i_){                                         \
      int j_ = 8*i_ + wid;                                                  \
      const unsigned char* src_; int dst_;                                  \
      if (j_ < 16){ src_ = kh_ + (size_t)j_*1024;        dst_ = j_*1024; }  \
      else if (j_ < 32){ src_ = kl_ + (size_t)(j_-16)*1024; dst_ = 16384 + (j_-16)*1024; } \
      else { src_ = vt_ + (size_t)(j_-32)*1024;          dst_ = 32768 + (j_-32)*1024; } \
      gll16(src_ + (size_t)lane*16, bb_ + dst_);                            \
    }                                                                       \
  } while(0)

  STAGE(0, 0);
  __syncthreads();                      // drains vmcnt(0): tile 0 ready
  int cur = 0;

  for (int t = 0; t < NT; ++t){
    // prefetch next tile into the other buffer BEFORE compute (T3-lite)
    if (t + 1 < NT) STAGE(t + 1, cur ^ 1);

    const char* B = smem + cur*BUFSZ;   // KH +0, KL +16K, VT +32K

    // ---- S = Q.K^T (bf16x3)
    f32x4 s0 = (f32x4){0.f,0.f,0.f,0.f}, s1 = (f32x4){0.f,0.f,0.f,0.f};
    __builtin_amdgcn_s_setprio(1);
    #pragma unroll
    for (int ks = 0; ks < 8; ++ks){
      int kb = 64*ks + 16*g;
      int o0 = c*512 + (kb ^ ((c & 7) << 4));
      int o1 = (16 + c)*512 + (kb ^ (((16 + c) & 7) << 4));
      s16x8 bh0 = *(const s16x8*)(B + o0);
      s16x8 bl0 = *(const s16x8*)(B + 16384 + o0);
      s16x8 bh1 = *(const s16x8*)(B + o1);
      s16x8 bl1 = *(const s16x8*)(B + 16384 + o1);
      s0 = __builtin_amdgcn_mfma_f32_16x16x32_bf16(qh[ks], bh0, s0, 0,0,0);
      s1 = __builtin_amdgcn_mfma_f32_16x16x32_bf16(qh[ks], bh1, s1, 0,0,0);
      s0 = __builtin_amdgcn_mfma_f32_16x16x32_bf16(ql[ks], bh0, s0, 0,0,0);
      s1 = __builtin_amdgcn_mfma_f32_16x16x32_bf16(ql[ks], bh1, s1, 0,0,0);
      s0 = __builtin_amdgcn_mfma_f32_16x16x32_bf16(qh[ks], bl0, s0, 0,0,0);
      s1 = __builtin_amdgcn_mfma_f32_16x16x32_bf16(qh[ks], bl1, s1, 0,0,0);
    }
    __builtin_amdgcn_s_setprio(0);

    // ---- online softmax; P packed b32 per lane per r (wave-private rows)
    float scl[4];
    #pragma unroll
    for (int r = 0; r < 4; ++r){
      float v = fmaxf(s0[r], s1[r]);
      v = fmaxf(v, __shfl_xor(v, 1)); v = fmaxf(v, __shfl_xor(v, 2));
      v = fmaxf(v, __shfl_xor(v, 4)); v = fmaxf(v, __shfl_xor(v, 8));
      float mo = m_run[r];
      float mn = fmaxf(mo, v);
      m_run[r] = mn;
      float sc = __expf(mo - mn);
      scl[r] = sc;
      float p0 = __expf(s0[r] - mn);
      float p1 = __expf(s1[r] - mn);
      float ps = p0 + p1;
      ps += __shfl_xor(ps, 1); ps += __shfl_xor(ps, 2);
      ps += __shfl_xor(ps, 4); ps += __shfl_xor(ps, 8);
      l_run[r] = l_run[r]*sc + ps;
      int qr = 16*wid + 4*g + r;
      unsigned pk = (unsigned)f2bf(p0) | ((unsigned)f2bf(p1) << 16);
      *(unsigned*)(smem + SM_P + qr*64 + ((4*c) ^ (r << 4))) = pk;
    }
    #pragma unroll
    for (int dt = 0; dt < 16; ++dt){
      o[dt][0] *= scl[0]; o[dt][1] *= scl[1]; o[dt][2] *= scl[2]; o[dt][3] *= scl[3];
    }

    // ---- PV
    {
      int q2 = 16*wid + c;
      s16x8 pa = *(const s16x8*)(smem + SM_P + q2*64 + ((16*g) ^ ((q2 & 3) << 4)));
      __builtin_amdgcn_s_setprio(1);
      #pragma unroll
      for (int dt = 0; dt < 16; ++dt){
        int vrow = 16*dt + c;
        s16x8 vb = *(const s16x8*)(B + 32768 + vrow*64 + ((16*g) ^ (((vrow >> 2) & 3) << 4)));
        o[dt] = __builtin_amdgcn_mfma_f32_16x16x32_bf16(pa, vb, o[dt], 0,0,0);
      }
      __builtin_amdgcn_s_setprio(0);
    }

    __syncthreads();                    // one barrier/tile; also drains prefetch
    cur ^= 1;
  }

  // ---- normalize O, park bf16 in LDS (wave-private rows; reuses buffer area)
  {
    float inv[4];
    #pragma unroll
    for (int r = 0; r < 4; ++r) inv[r] = 1.0f / l_run[r];
    #pragma unroll
    for (int dt = 0; dt < 16; ++dt){
      #pragma unroll
      for (int r = 0; r < 4; ++r){
        int qr = 16*wid + 4*g + r;
        int dcol = 16*dt + c;
        float val = o[dt][r] * inv[r];
        *(short*)(smem + SM_O + qr*512 + ((2*dcol) ^ ((qr & 7) << 4))) = (short)f2bf(val);
      }
    }
  }

  // ---- FC: W read directly from L2-hot bf16 ws copy
  f32x4 fa[8];
  #pragma unroll
  for (int i = 0; i < 8; ++i) fa[i] = (f32x4){0.f,0.f,0.f,0.f};

  #pragma unroll
  for (int fc = 0; fc < 8; ++fc){
    #pragma unroll
    for (int ksl = 0; ksl < 4; ++ksl){
      const int cidx = (fc & 1)*4 + ksl;
      s16x8 a;
      if (fc < 2){
        a = qh[cidx];
      } else {
        int q2 = 16*wid + c;
        s16x8 o8 = *(const s16x8*)(smem + SM_O + q2*512 + ((64*cidx + 16*g) ^ ((q2 & 7) << 4)));
        if (fc < 4){ a = o8; }
        else {
          #pragma unroll
          for (int j = 0; j < 8; ++j){
            float qf = bf2f((unsigned short)qh[cidx][j]) + bf2f((unsigned short)ql[cidx][j]);
            float of = bf2f((unsigned short)o8[j]);
            float fv = (fc < 6) ? (qf - of) : (qf * of);
            a[j] = (short)f2bf(fv);
          }
        }
      }
      #pragma unroll
      for (int nt = 0; nt < 8; ++nt){
        s16x8 wb = *(const s16x8*)(Wp + (size_t)(16*nt + c)*2048 + 2*(fc*128 + 32*ksl + 8*g));
        fa[nt] = __builtin_amdgcn_mfma_f32_16x16x32_bf16(a, wb, fa[nt], 0,0,0);
      }
    }
  }

  #pragma unroll
  for (int nt = 0; nt < 8; ++nt){
    float bs = bia[16*nt + c];
    #pragma unroll
    for (int r = 0; r < 4; ++r){
      int qr = 16*wid + 4*g + r;
      float v = fa[nt][r] + bs;
      v = fmaxf(v, 0.f);
      outp[(size_t)qr*NH + 16*nt + c] = v;
    }
  }
}

// ================= fallback (round-1 kernel, used if ws too small) =================

__global__ __launch_bounds__(256, 2)
void lm_fallback(const float* __restrict__ cs, const float* __restrict__ rs,
                 const float* __restrict__ W1, const float* __restrict__ b1,
                 const float* __restrict__ W2, const float* __restrict__ b2,
                 float* __restrict__ out)
{
  __shared__ __align__(16) char smem[65536];
  const int tid  = threadIdx.x;
  const int lane = tid & 63;
  const int wid  = tid >> 6;
  const int c    = lane & 15;
  const int g    = lane >> 4;

  int bid = blockIdx.x;
  int dir, b, qt;
  if (bid < 1024){ int xcd = bid & 7, inner = bid >> 3;
    b = (xcd << 2) + (inner >> 5); qt = inner & 31; dir = 0; }
  else { int t2 = bid - 1024; int xcd = t2 & 7, inner = t2 >> 3;
    b = (xcd << 2) + (inner >> 3); qt = inner & 7; dir = 1; }

  const float* Q   = dir == 0 ? cs + ((size_t)b*NLC + qt*64)*ND
                              : rs + ((size_t)b*NLR + qt*64)*ND;
  const float* KV  = dir == 0 ? rs + (size_t)b*NLR*ND : cs + (size_t)b*NLC*ND;
  const int    NK  = dir == 0 ? NLR : NLC;
  const float* Wm  = dir == 0 ? W1 : W2;
  const float* bia = dir == 0 ? b1 : b2;
  float* outp = dir == 0 ? out + ((size_t)b*NLC + qt*64)*NH
                         : out + (size_t)NB*NLC*NH + ((size_t)b*NLR + qt*64)*NH;

  s16x8 qh[8], ql[8];
  {
    const float* qrow = Q + (size_t)(16*wid + c)*ND;
    #pragma unroll
    for (int ks = 0; ks < 8; ++ks){
      float4 x0 = *(const float4*)(qrow + 32*ks + 8*g);
      float4 x1 = *(const float4*)(qrow + 32*ks + 8*g + 4);
      float xs[8] = {x0.x,x0.y,x0.z,x0.w,x1.x,x1.y,x1.z,x1.w};
      #pragma unroll
      for (int j = 0; j < 8; ++j){ short h,l; splitbf(xs[j],h,l); qh[ks][j]=h; ql[ks][j]=l; }
    }
  }

  f32x4 o[16];
  #pragma unroll
  for (int i = 0; i < 16; ++i) o[i] = (f32x4){0.f,0.f,0.f,0.f};
  float m_run[4] = {-INFINITY,-INFINITY,-INFINITY,-INFINITY};
  float l_run[4] = {0.f,0.f,0.f,0.f};

  const int ntile = NK >> 5;
  for (int t = 0; t < ntile; ++t){
    __syncthreads();
    {
      const float* KVt = KV + (size_t)t*32*ND;
      #pragma unroll
      for (int p = 0; p < 8; ++p){
        int kvloc = p*4 + wid;
        float4 x = *((const float4*)(KVt + kvloc*ND) + lane);
        short h0,l0,h1,l1,h2,l2,h3,l3;
        splitbf(x.x,h0,l0); splitbf(x.y,h1,l1); splitbf(x.z,h2,l2); splitbf(x.w,h3,l3);
        int roff = kvloc*512 + ((8*lane) ^ ((kvloc&7)<<4));
        *(s16x4*)(smem + 0     + roff) = (s16x4){h0,h1,h2,h3};
        *(s16x4*)(smem + 16384 + roff) = (s16x4){l0,l1,l2,l3};
        int d0 = 4*lane;
        short hs[4] = {h0,h1,h2,h3};
        #pragma unroll
        for (int j = 0; j < 4; ++j){
          int dr = d0 + j;
          int voff = dr*64 + ((2*kvloc) ^ (((dr>>2)&3)<<4));
          *(short*)(smem + 32768 + voff) = hs[j];
        }
      }
    }
    __syncthreads();

    f32x4 s0 = (f32x4){0.f,0.f,0.f,0.f}, s1 = (f32x4){0.f,0.f,0.f,0.f};
    #pragma unroll
    for (int ks = 0; ks < 8; ++ks){
      int kb = 64*ks + 16*g;
      int o0 = c*512 + (kb ^ ((c&7)<<4));
      int o1 = (16+c)*512 + (kb ^ (((16+c)&7)<<4));
      s16x8 bh0 = *(const s16x8*)(smem + 0     + o0);
      s16x8 bl0 = *(const s16x8*)(smem + 16384 + o0);
      s16x8 bh1 = *(const s16x8*)(smem + 0     + o1);
      s16x8 bl1 = *(const s16x8*)(smem + 16384 + o1);
      s0 = __builtin_amdgcn_mfma_f32_16x16x32_bf16(qh[ks], bh0, s0, 0,0,0);
      s1 = __builtin_amdgcn_mfma_f32_16x16x32_bf16(qh[ks], bh1, s1, 0,0,0);
      s0 = __builtin_amdgcn_mfma_f32_16x16x32_bf16(ql[ks], bh0, s0, 0,0,0);
      s1 = __builtin_amdgcn_mfma_f32_16x16x32_bf16(ql[ks], bh1, s1, 0,0,0);
      s0 = __builtin_amdgcn_mfma_f32_16x16x32_bf16(qh[ks], bl0, s0, 0,0,0);
      s1 = __builtin_amdgcn_mfma_f32_16x16x32_bf16(qh[ks], bl1, s1, 0,0,0);
    }

    float scl[4];
    #pragma unroll
    for (int r = 0; r < 4; ++r){
      float v = fmaxf(s0[r], s1[r]);
      v = fmaxf(v, __shfl_xor(v, 1)); v = fmaxf(v, __shfl_xor(v, 2));
      v = fmaxf(v, __shfl_xor(v, 4)); v = fmaxf(v, __shfl_xor(v, 8));
      float mo = m_run[r];
      float mn = fmaxf(mo, v);
      m_run[r] = mn;
      float sc = __expf(mo - mn);
      scl[r] = sc;
      float p0 = __expf(s0[r] - mn);
      float p1 = __expf(s1[r] - mn);
      float ps = p0 + p1;
      ps += __shfl_xor(ps, 1); ps += __shfl_xor(ps, 2);
      ps += __shfl_xor(ps, 4); ps += __shfl_xor(ps, 8);
      l_run[r] = l_run[r]*sc + ps;
      int q = 16*wid + 4*g + r;
      int pb = q*64;
      *(short*)(smem + 49152 + pb + (( 2*c     ) ^ (r<<4))) = (short)f2bf(p0);
      *(short*)(smem + 49152 + pb + ((32 + 2*c ) ^ (r<<4))) = (short)f2bf(p1);
    }
    #pragma unroll
    for (int dt = 0; dt < 16; ++dt){
      o[dt][0] *= scl[0]; o[dt][1] *= scl[1]; o[dt][2] *= scl[2]; o[dt][3] *= scl[3];
    }

    {
      int q = 16*wid + c;
      s16x8 pa = *(const s16x8*)(smem + 49152 + q*64 + ((16*g) ^ ((q&3)<<4)));
      #pragma unroll
      for (int dt = 0; dt < 16; ++dt){
        int vrow = 16*dt + c;
        s16x8 vb = *(const s16x8*)(smem + 32768 + vrow*64 + ((16*g) ^ (((vrow>>2)&3)<<4)));
        o[dt] = __builtin_amdgcn_mfma_f32_16x16x32_bf16(pa, vb, o[dt], 0,0,0);
      }
    }
  }

  __syncthreads();
  {
    float inv[4];
    #pragma unroll
    for (int r = 0; r < 4; ++r) inv[r] = 1.0f / l_run[r];
    #pragma unroll
    for (int dt = 0; dt < 16; ++dt){
      #pragma unroll
      for (int r = 0; r < 4; ++r){
        int q = 16*wid + 4*g + r;
        int dcol = 16*dt + c;
        float val = o[dt][r] * inv[r];
        *(short*)(smem + 0 + q*512 + ((2*dcol) ^ ((q&7)<<4))) = (short)f2bf(val);
      }
    }
  }

  f32x4 fa[8];
  #pragma unroll
  for (int i = 0; i < 8; ++i) fa[i] = (f32x4){0.f,0.f,0.f,0.f};

  #pragma unroll
  for (int fc = 0; fc < 8; ++fc){
    __syncthreads();
    #pragma unroll
    for (int p = 0; p < 8; ++p){
      int h  = p*16 + (tid >> 4);
      int fl = (tid & 15) * 8;
      const float* srcw = Wm + (size_t)h*1024 + fc*128 + fl;
      float4 x0 = *(const float4*)srcw;
      float4 x1 = *(const float4*)(srcw + 4);
      s16x8 w8;
      w8[0]=(short)f2bf(x0.x); w8[1]=(short)f2bf(x0.y); w8[2]=(short)f2bf(x0.z); w8[3]=(short)f2bf(x0.w);
      w8[4]=(short)f2bf(x1.x); w8[5]=(short)f2bf(x1.y); w8[6]=(short)f2bf(x1.z); w8[7]=(short)f2bf(x1.w);
      *(s16x8*)(smem + 32768 + h*256 + ((2*fl) ^ ((h&7)<<4))) = w8;
    }
    __syncthreads();
    #pragma unroll
    for (int ks = 0; ks < 4; ++ks){
      const int cidx = (fc & 1)*4 + ks;
      s16x8 a;
      if (fc < 2){
        a = qh[cidx];
      } else {
        int q = 16*wid + c;
        s16x8 o8 = *(const s16x8*)(smem + 0 + q*512 + ((64*cidx + 16*g) ^ ((q&7)<<4)));
        if (fc < 4){ a = o8; }
        else {
          #pragma unroll
          for (int j = 0; j < 8; ++j){
            float qf = bf2f((unsigned short)qh[cidx][j]) + bf2f((unsigned short)ql[cidx][j]);
            float of = bf2f((unsigned short)o8[j]);
            float fv = (fc < 6) ? (qf - of) : (qf * of);
            a[j] = (short)f2bf(fv);
          }
        }
      }
      #pragma unroll
      for (int nt = 0; nt < 8; ++nt){
        int hh = 16*nt + c;
        s16x8 wb = *(const s16x8*)(smem + 32768 + hh*256 + ((64*ks + 16*g) ^ ((hh&7)<<4)));
        fa[nt] = __builtin_amdgcn_mfma_f32_16x16x32_bf16(a, wb, fa[nt], 0,0,0);
      }
    }
  }

  #pragma unroll
  for (int nt = 0; nt < 8; ++nt){
    float bs = bia[16*nt + c];
    #pragma unroll
    for (int r = 0; r < 4; ++r){
      int q = 16*wid + 4*g + r;
      float v = fa[nt][r] + bs;
      v = fmaxf(v, 0.f);
      outp[(size_t)q*NH + 16*nt + c] = v;
    }
  }
}

extern "C" void kernel_launch(void* const* d_in, const int* in_sizes, int n_in,
                              void* d_out, int out_size, void* d_ws, size_t ws_size,
                              hipStream_t stream) {
  (void)in_sizes; (void)n_in; (void)out_size;
  const float* cs = (const float*)d_in[0];
  const float* rs = (const float*)d_in[1];
  const float* W1 = (const float*)d_in[2];
  const float* b1 = (const float*)d_in[3];
  const float* W2 = (const float*)d_in[4];
  const float* b2 = (const float*)d_in[5];
  float* out = (float*)d_out;

  if (ws_size >= WS_NEED){
    unsigned char* ws = (unsigned char*)d_ws;
    hipLaunchKernelGGL(prep_rows, dim3(20608), dim3(256), 0, stream, cs, rs, W1, W2, ws);
    hipLaunchKernelGGL(prep_T,    dim3(2560),  dim3(256), 0, stream, cs, rs, ws);
    hipLaunchKernelGGL(lm_main,   dim3(640),   dim3(512), 0, stream, ws, b1, b2, out);
  } else {
    hipLaunchKernelGGL(lm_fallback, dim3(1280), dim3(256), 0, stream,
                       cs, rs, W1, b1, W2, b2, out);
  }
}

// Round 5
// 443.622 us; speedup vs baseline: 1.7528x; 1.0917x over previous
//
#include <hip/hip_runtime.h>

// LocalMatching fused kernel for MI355X (gfx950) — round 5.
// r4 + swapped QK^T (S^T = K·Q^T): softmax fully in-register (2 shuffles/tile),
// P packed straight into the PV B-fragment (no P LDS at all). V^T workspace
// layout re-permuted (nu) so PV's A/B kv-maps agree. FC phase unchanged.

#define NB  32
#define NLC 2048
#define NLR 512
#define ND  256
#define NH  128

typedef float f32x4 __attribute__((ext_vector_type(4)));
typedef short s16x8 __attribute__((ext_vector_type(8)));
typedef short s16x4 __attribute__((ext_vector_type(4)));
typedef int   i32x4 __attribute__((ext_vector_type(4)));

// ---- workspace layout (bytes) ----
#define WS_CSH 0ull
#define WS_CSL (WS_CSH + 33554432ull)
#define WS_RSH (WS_CSL + 33554432ull)
#define WS_RSL (WS_RSH + 8388608ull)
#define WS_RST (WS_RSL + 8388608ull)
#define WS_CST (WS_RST + 8388608ull)
#define WS_WH  (WS_CST + 33554432ull)
#define WS_NEED (WS_WH + 524288ull)

// ---- main-kernel LDS: buf0 [0,48K) buf1 [48K,96K); FC: O at [0,64K)
#define BUFSZ 49152
#define SM_O  0

__device__ __forceinline__ unsigned short f2bf(float x){
  unsigned u = __builtin_bit_cast(unsigned, x);
  u += 0x7FFFu + ((u >> 16) & 1u);
  return (unsigned short)(u >> 16);
}
__device__ __forceinline__ float bf2f(unsigned short h){
  unsigned u = ((unsigned)h) << 16;
  return __builtin_bit_cast(float, u);
}
__device__ __forceinline__ void splitbf(float x, short &hi, short &lo){
  unsigned short h = f2bf(x);
  float r = x - bf2f(h);
  hi = (short)h;
  lo = (short)f2bf(r);
}
__device__ __forceinline__ void gll16(const void* g, void* l){
  __builtin_amdgcn_global_load_lds((const __attribute__((address_space(1))) void*)g,
                                   (__attribute__((address_space(3))) void*)l, 16, 0, 0);
}

// ================= prep kernels =================

__global__ __launch_bounds__(256)
void prep_rows(const float* __restrict__ cs, const float* __restrict__ rs,
               const float* __restrict__ W1, const float* __restrict__ W2,
               unsigned char* __restrict__ ws)
{
  const int tid = threadIdx.x, lane = tid & 63, wid = tid >> 6;
  const int bid = blockIdx.x;
  if (bid < 20480){
    const float* srcrow; unsigned char *dsth, *dstl; int kvl;
    if (bid < 16384){
      int row = bid*4 + wid;
      int b = row >> 11, pos = row & 2047, t = pos >> 5; kvl = pos & 31;
      srcrow = cs + (size_t)row*ND;
      size_t off = ((size_t)(b*64 + t)*32 + kvl)*512;
      dsth = ws + WS_CSH + off; dstl = ws + WS_CSL + off;
    } else {
      int row = (bid - 16384)*4 + wid;
      int b = row >> 9, pos = row & 511, t = pos >> 5; kvl = pos & 31;
      srcrow = rs + (size_t)row*ND;
      size_t off = ((size_t)(b*16 + t)*32 + kvl)*512;
      dsth = ws + WS_RSH + off; dstl = ws + WS_RSL + off;
    }
    float4 x = *((const float4*)srcrow + lane);
    short h0,l0,h1,l1,h2,l2,h3,l3;
    splitbf(x.x,h0,l0); splitbf(x.y,h1,l1); splitbf(x.z,h2,l2); splitbf(x.w,h3,l3);
    int boff = (8*lane) ^ ((kvl & 7) << 4);
    *(s16x4*)(dsth + boff) = (s16x4){h0,h1,h2,h3};
    *(s16x4*)(dstl + boff) = (s16x4){l0,l1,l2,l3};
  } else {
    int idx = (bid - 20480)*2048 + tid*8;
    const float* srcw = (idx < 131072) ? (W1 + idx) : (W2 + (idx - 131072));
    float4 a = *(const float4*)srcw;
    float4 c4 = *((const float4*)srcw + 1);
    s16x8 h;
    h[0]=(short)f2bf(a.x); h[1]=(short)f2bf(a.y); h[2]=(short)f2bf(a.z); h[3]=(short)f2bf(a.w);
    h[4]=(short)f2bf(c4.x); h[5]=(short)f2bf(c4.y); h[6]=(short)f2bf(c4.z); h[7]=(short)f2bf(c4.w);
    *(s16x8*)(ws + WS_WH + (size_t)idx*2) = h;
  }
}

__global__ __launch_bounds__(256)
void prep_T(const float* __restrict__ cs, const float* __restrict__ rs,
            unsigned char* __restrict__ ws)
{
  __shared__ float tile[32][256];
  const int tid = threadIdx.x, lane = tid & 63, wid = tid >> 6;
  const int bid = blockIdx.x;
  const float* src; unsigned char* dst;
  if (bid < 512){ int b = bid >> 4, t = bid & 15;
    src = rs + ((size_t)b*NLR + t*32)*ND;
    dst = ws + WS_RST + (size_t)bid*16384;
  } else { int b2 = bid - 512; int b = b2 >> 6, t = b2 & 63;
    src = cs + ((size_t)b*NLC + t*32)*ND;
    dst = ws + WS_CST + (size_t)b2*16384;
  }
  #pragma unroll
  for (int i = 0; i < 8; ++i){
    int r = wid*8 + i;
    float4 x = *((const float4*)(src + (size_t)r*ND) + lane);
    *(float4*)&tile[r][lane*4] = x;
  }
  __syncthreads();
  const int d = tid;
  const int swzc = (d >> 2) & 3;
  unsigned char* orow = dst + d*64;
  #pragma unroll
  for (int ci = 0; ci < 4; ++ci){
    int sg = ci ^ swzc;
    s16x8 w;
    #pragma unroll
    for (int j = 0; j < 8; ++j){
      // nu-permutation: slot s=8*sg+j holds kv = 4*sg + (j&3) + 16*((j>>2)&1)
      int kvl = 4*sg + (j & 3) + 16*((j >> 2) & 1);
      w[j] = (short)f2bf(tile[kvl][d]);
    }
    *(s16x8*)(orow + 16*ci) = w;
  }
}

// ================= main kernel =================

__global__ __launch_bounds__(512, 2)
void lm_main(const unsigned char* __restrict__ ws,
             const float* __restrict__ b1, const float* __restrict__ b2,
             float* __restrict__ out)
{
  __shared__ __align__(16) char smem[98304];

  const int tid  = threadIdx.x;
  const int lane = tid & 63;
  const int wid  = tid >> 6;        // 0..7, owns q rows [16*wid, 16*wid+16)
  const int c    = lane & 15;
  const int g    = lane >> 4;

  // dir1 (heavy, 64 tiles) first: bids [0,128); dir0: [128,640)
  int bid = blockIdx.x;
  int dir, b, qt;
  if (bid < 128){ dir = 1; int xcd = bid & 7, inner = bid >> 3;
    b = xcd*4 + (inner >> 2); qt = inner & 3; }
  else { dir = 0; int t2 = bid - 128; int xcd = t2 & 7, inner = t2 >> 3;
    b = xcd*4 + (inner >> 4); qt = inner & 15; }

  const unsigned char *QH, *QL, *KH, *KL, *VT;
  int NT;
  if (dir == 0){
    QH = ws + WS_CSH + (size_t)b*64*16384;  QL = ws + WS_CSL + (size_t)b*64*16384;
    KH = ws + WS_RSH + (size_t)b*16*16384;  KL = ws + WS_RSL + (size_t)b*16*16384;
    VT = ws + WS_RST + (size_t)b*16*16384;  NT = 16;
  } else {
    QH = ws + WS_RSH + (size_t)b*16*16384;  QL = ws + WS_RSL + (size_t)b*16*16384;
    KH = ws + WS_CSH + (size_t)b*64*16384;  KL = ws + WS_CSL + (size_t)b*64*16384;
    VT = ws + WS_CST + (size_t)b*64*16384;  NT = 64;
  }
  const unsigned char* Wp = ws + WS_WH + (size_t)dir*262144;
  const float* bia = dir ? b2 : b1;
  float* outp = dir == 0 ? out + ((size_t)b*NLC + qt*128)*NH
                         : out + (size_t)NB*NLC*NH + ((size_t)b*NLR + qt*128)*NH;

  // ---- Q fragments (hi/lo) held in registers all kernel (row q = qt*128+16*wid+c)
  s16x8 qh[8], ql[8];
  {
    int q = qt*128 + 16*wid + c;
    const unsigned char* qrowH = QH + (size_t)(q >> 5)*16384 + (size_t)(q & 31)*512;
    const unsigned char* qrowL = QL + (size_t)(q >> 5)*16384 + (size_t)(q & 31)*512;
    int qx = (q & 7) << 4;
    #pragma unroll
    for (int ks = 0; ks < 8; ++ks){
      int off = (64*ks + 16*g) ^ qx;
      qh[ks] = *(const s16x8*)(qrowH + off);
      ql[ks] = *(const s16x8*)(qrowL + off);
    }
  }

  // o[m][r] = O[q = 16*wid+c][d = 16*m + 4*g + r]
  f32x4 o[16];
  #pragma unroll
  for (int i = 0; i < 16; ++i) o[i] = (f32x4){0.f,0.f,0.f,0.f};
  float m_run = -INFINITY;
  float l_run = 0.f;

  // ---- stage helper: 48 gll16 per tile, 6 per wave, linear LDS dest
  #define STAGE(tt, bsel) do {                                              \
    const unsigned char* kh_ = KH + (size_t)(tt)*16384;                     \
    const unsigned char* kl_ = KL + (size_t)(tt)*16384;                     \
    const unsigned char* vt_ = VT + (size_t)(tt)*16384;                     \
    char* bb_ = smem + (bsel)*BUFSZ;                                        \
    _Pragma("unroll")                                                       \
    for (int i_ = 0; i_ < 6; ++i_){                                         \
      int j_ = 8*i_ + wid;                                                  \
      const unsigned char* src_; int dst_;                                  \
      if (j_ < 16){ src_ = kh_ + (size_t)j_*1024;        dst_ = j_*1024; }  \
      else if (j_ < 32){ src_ = kl_ + (size_t)(j_-16)*1024; dst_ = 16384 + (j_-16)*1024; } \
      else { src_ = vt_ + (size_t)(j_-32)*1024;          dst_ = 32768 + (j_-32)*1024; } \
      gll16(src_ + (size_t)lane*16, bb_ + dst_);                            \
    }                                                                       \
  } while(0)

  STAGE(0, 0);
  __syncthreads();                      // drains vmcnt(0): tile 0 ready
  int cur = 0;

  for (int t = 0; t < NT; ++t){
    if (t + 1 < NT) STAGE(t + 1, cur ^ 1);

    const char* B = smem + cur*BUFSZ;   // KH +0, KL +16K, VT +32K

    // ---- S^T = K·Q^T (bf16x3). A = K fragments (LDS), B = Q fragments (regs).
    // D-map: lane(c,g) reg r -> S[q = 16*wid+c][kv = 4*g+r] (s0) / 16+4*g+r (s1)
    f32x4 s0a = (f32x4){0.f,0.f,0.f,0.f}, s0b = (f32x4){0.f,0.f,0.f,0.f};
    f32x4 s1a = (f32x4){0.f,0.f,0.f,0.f}, s1b = (f32x4){0.f,0.f,0.f,0.f};
    __builtin_amdgcn_s_setprio(1);
    #pragma unroll
    for (int ks = 0; ks < 8; ++ks){
      int kb = 64*ks + 16*g;
      int o0 = c*512 + (kb ^ ((c & 7) << 4));
      int o1 = (16 + c)*512 + (kb ^ (((16 + c) & 7) << 4));
      s16x8 bh0 = *(const s16x8*)(B + o0);
      s16x8 bl0 = *(const s16x8*)(B + 16384 + o0);
      s16x8 bh1 = *(const s16x8*)(B + o1);
      s16x8 bl1 = *(const s16x8*)(B + 16384 + o1);
      if (ks & 1){
        s0b = __builtin_amdgcn_mfma_f32_16x16x32_bf16(bh0, qh[ks], s0b, 0,0,0);
        s1b = __builtin_amdgcn_mfma_f32_16x16x32_bf16(bh1, qh[ks], s1b, 0,0,0);
        s0b = __builtin_amdgcn_mfma_f32_16x16x32_bf16(bh0, ql[ks], s0b, 0,0,0);
        s1b = __builtin_amdgcn_mfma_f32_16x16x32_bf16(bh1, ql[ks], s1b, 0,0,0);
        s0b = __builtin_amdgcn_mfma_f32_16x16x32_bf16(bl0, qh[ks], s0b, 0,0,0);
        s1b = __builtin_amdgcn_mfma_f32_16x16x32_bf16(bl1, qh[ks], s1b, 0,0,0);
      } else {
        s0a = __builtin_amdgcn_mfma_f32_16x16x32_bf16(bh0, qh[ks], s0a, 0,0,0);
        s1a = __builtin_amdgcn_mfma_f32_16x16x32_bf16(bh1, qh[ks], s1a, 0,0,0);
        s0a = __builtin_amdgcn_mfma_f32_16x16x32_bf16(bh0, ql[ks], s0a, 0,0,0);
        s1a = __builtin_amdgcn_mfma_f32_16x16x32_bf16(bh1, ql[ks], s1a, 0,0,0);
        s0a = __builtin_amdgcn_mfma_f32_16x16x32_bf16(bl0, qh[ks], s0a, 0,0,0);
        s1a = __builtin_amdgcn_mfma_f32_16x16x32_bf16(bl1, qh[ks], s1a, 0,0,0);
      }
    }
    __builtin_amdgcn_s_setprio(0);
    f32x4 s0 = s0a + s0b;
    f32x4 s1 = s1a + s1b;

    // ---- in-register online softmax for q = 16*wid + c (32 kv values: 8 in-lane × 4 g)
    float v = fmaxf(fmaxf(fmaxf(s0[0], s0[1]), fmaxf(s0[2], s0[3])),
                    fmaxf(fmaxf(s1[0], s1[1]), fmaxf(s1[2], s1[3])));
    v = fmaxf(v, __shfl_xor(v, 16));
    v = fmaxf(v, __shfl_xor(v, 32));
    float mn  = fmaxf(m_run, v);
    float scl = __expf(m_run - mn);     // 0 on first tile
    m_run = mn;
    float p0_0 = __expf(s0[0] - mn), p0_1 = __expf(s0[1] - mn);
    float p0_2 = __expf(s0[2] - mn), p0_3 = __expf(s0[3] - mn);
    float p1_0 = __expf(s1[0] - mn), p1_1 = __expf(s1[1] - mn);
    float p1_2 = __expf(s1[2] - mn), p1_3 = __expf(s1[3] - mn);
    float ps = ((p0_0 + p0_1) + (p0_2 + p0_3)) + ((p1_0 + p1_1) + (p1_2 + p1_3));
    ps += __shfl_xor(ps, 16);
    ps += __shfl_xor(ps, 32);
    l_run = l_run * scl + ps;

    // ---- pack P^T B-fragment: slot(g,j) must hold kv = 4g + (j&3) + 16*((j>>2)&1)
    unsigned pw0 = (unsigned)f2bf(p0_0) | ((unsigned)f2bf(p0_1) << 16);
    unsigned pw1 = (unsigned)f2bf(p0_2) | ((unsigned)f2bf(p0_3) << 16);
    unsigned pw2 = (unsigned)f2bf(p1_0) | ((unsigned)f2bf(p1_1) << 16);
    unsigned pw3 = (unsigned)f2bf(p1_2) | ((unsigned)f2bf(p1_3) << 16);
    s16x8 pb = __builtin_bit_cast(s16x8, (i32x4){(int)pw0, (int)pw1, (int)pw2, (int)pw3});

    // ---- rescale O by scl (single scalar per lane)
    #pragma unroll
    for (int m = 0; m < 16; ++m){
      o[m][0] *= scl; o[m][1] *= scl; o[m][2] *= scl; o[m][3] *= scl;
    }

    // ---- PV: O^T += V^T · P^T   (A = V^T from LDS, B = pb regs)
    __builtin_amdgcn_s_setprio(1);
    #pragma unroll
    for (int m = 0; m < 16; ++m){
      int vrow = 16*m + c;
      s16x8 va = *(const s16x8*)(B + 32768 + vrow*64 + ((16*g) ^ (((vrow >> 2) & 3) << 4)));
      o[m] = __builtin_amdgcn_mfma_f32_16x16x32_bf16(va, pb, o[m], 0,0,0);
    }
    __builtin_amdgcn_s_setprio(0);

    __syncthreads();                    // one barrier/tile; also drains prefetch
    cur ^= 1;
  }

  // ---- normalize O, park bf16 in LDS rows [q][d] (wave-private rows)
  {
    float inv = 1.0f / l_run;
    int q = 16*wid + c;
    int swz = (q & 7) << 4;
    #pragma unroll
    for (int m = 0; m < 16; ++m){
      unsigned u0 = (unsigned)f2bf(o[m][0]*inv) | ((unsigned)f2bf(o[m][1]*inv) << 16);
      unsigned u1 = (unsigned)f2bf(o[m][2]*inv) | ((unsigned)f2bf(o[m][3]*inv) << 16);
      int byte = q*512 + ((32*m + 8*g) ^ swz);
      *(uint2*)(smem + SM_O + byte) = (uint2){u0, u1};
    }
  }
  __syncthreads();

  // ---- FC: out = relu(concat(q, o, q-o, q*o)·W^T + b); W from L2-hot bf16 ws
  f32x4 fa[8];
  #pragma unroll
  for (int i = 0; i < 8; ++i) fa[i] = (f32x4){0.f,0.f,0.f,0.f};

  #pragma unroll
  for (int fc = 0; fc < 8; ++fc){
    #pragma unroll
    for (int ksl = 0; ksl < 4; ++ksl){
      const int cidx = (fc & 1)*4 + ksl;
      s16x8 a;
      if (fc < 2){
        a = qh[cidx];
      } else {
        int q2 = 16*wid + c;
        s16x8 o8 = *(const s16x8*)(smem + SM_O + q2*512 + ((64*cidx + 16*g) ^ ((q2 & 7) << 4)));
        if (fc < 4){ a = o8; }
        else {
          #pragma unroll
          for (int j = 0; j < 8; ++j){
            float qf = bf2f((unsigned short)qh[cidx][j]) + bf2f((unsigned short)ql[cidx][j]);
            float of = bf2f((unsigned short)o8[j]);
            float fv = (fc < 6) ? (qf - of) : (qf * of);
            a[j] = (short)f2bf(fv);
          }
        }
      }
      #pragma unroll
      for (int nt = 0; nt < 8; ++nt){
        s16x8 wb = *(const s16x8*)(Wp + (size_t)(16*nt + c)*2048 + 2*(fc*128 + 32*ksl + 8*g));
        fa[nt] = __builtin_amdgcn_mfma_f32_16x16x32_bf16(a, wb, fa[nt], 0,0,0);
      }
    }
  }

  #pragma unroll
  for (int nt = 0; nt < 8; ++nt){
    float bs = bia[16*nt + c];
    #pragma unroll
    for (int r = 0; r < 4; ++r){
      int qr = 16*wid + 4*g + r;
      float v2 = fa[nt][r] + bs;
      v2 = fmaxf(v2, 0.f);
      outp[(size_t)qr*NH + 16*nt + c] = v2;
    }
  }
}

// ================= fallback (round-1 kernel, used if ws too small) =================

__global__ __launch_bounds__(256, 2)
void lm_fallback(const float* __restrict__ cs, const float* __restrict__ rs,
                 const float* __restrict__ W1, const float* __restrict__ b1,
                 const float* __restrict__ W2, const float* __restrict__ b2,
                 float* __restrict__ out)
{
  __shared__ __align__(16) char smem[65536];
  const int tid  = threadIdx.x;
  const int lane = tid & 63;
  const int wid  = tid >> 6;
  const int c    = lane & 15;
  const int g    = lane >> 4;

  int bid = blockIdx.x;
  int dir, b, qt;
  if (bid < 1024){ int xcd = bid & 7, inner = bid >> 3;
    b = (xcd << 2) + (inner >> 5); qt = inner & 31; dir = 0; }
  else { int t2 = bid - 1024; int xcd = t2 & 7, inner = t2 >> 3;
    b = (xcd << 2) + (inner >> 3); qt = inner & 7; dir = 1; }

  const float* Q   = dir == 0 ? cs + ((size_t)b*NLC + qt*64)*ND
                              : rs + ((size_t)b*NLR + qt*64)*ND;
  const float* KV  = dir == 0 ? rs + (size_t)b*NLR*ND : cs + (size_t)b*NLC*ND;
  const int    NK  = dir == 0 ? NLR : NLC;
  const float* Wm  = dir == 0 ? W1 : W2;
  const float* bia = dir == 0 ? b1 : b2;
  float* outp = dir == 0 ? out + ((size_t)b*NLC + qt*64)*NH
                         : out + (size_t)NB*NLC*NH + ((size_t)b*NLR + qt*64)*NH;

  s16x8 qh[8], ql[8];
  {
    const float* qrow = Q + (size_t)(16*wid + c)*ND;
    #pragma unroll
    for (int ks = 0; ks < 8; ++ks){
      float4 x0 = *(const float4*)(qrow + 32*ks + 8*g);
      float4 x1 = *(const float4*)(qrow + 32*ks + 8*g + 4);
      float xs[8] = {x0.x,x0.y,x0.z,x0.w,x1.x,x1.y,x1.z,x1.w};
      #pragma unroll
      for (int j = 0; j < 8; ++j){ short h,l; splitbf(xs[j],h,l); qh[ks][j]=h; ql[ks][j]=l; }
    }
  }

  f32x4 o[16];
  #pragma unroll
  for (int i = 0; i < 16; ++i) o[i] = (f32x4){0.f,0.f,0.f,0.f};
  float m_run[4] = {-INFINITY,-INFINITY,-INFINITY,-INFINITY};
  float l_run[4] = {0.f,0.f,0.f,0.f};

  const int ntile = NK >> 5;
  for (int t = 0; t < ntile; ++t){
    __syncthreads();
    {
      const float* KVt = KV + (size_t)t*32*ND;
      #pragma unroll
      for (int p = 0; p < 8; ++p){
        int kvloc = p*4 + wid;
        float4 x = *((const float4*)(KVt + kvloc*ND) + lane);
        short h0,l0,h1,l1,h2,l2,h3,l3;
        splitbf(x.x,h0,l0); splitbf(x.y,h1,l1); splitbf(x.z,h2,l2); splitbf(x.w,h3,l3);
        int roff = kvloc*512 + ((8*lane) ^ ((kvloc&7)<<4));
        *(s16x4*)(smem + 0     + roff) = (s16x4){h0,h1,h2,h3};
        *(s16x4*)(smem + 16384 + roff) = (s16x4){l0,l1,l2,l3};
        int d0 = 4*lane;
        short hs[4] = {h0,h1,h2,h3};
        #pragma unroll
        for (int j = 0; j < 4; ++j){
          int dr = d0 + j;
          int voff = dr*64 + ((2*kvloc) ^ (((dr>>2)&3)<<4));
          *(short*)(smem + 32768 + voff) = hs[j];
        }
      }
    }
    __syncthreads();

    f32x4 s0 = (f32x4){0.f,0.f,0.f,0.f}, s1 = (f32x4){0.f,0.f,0.f,0.f};
    #pragma unroll
    for (int ks = 0; ks < 8; ++ks){
      int kb = 64*ks + 16*g;
      int o0 = c*512 + (kb ^ ((c&7)<<4));
      int o1 = (16+c)*512 + (kb ^ (((16+c)&7)<<4));
      s16x8 bh0 = *(const s16x8*)(smem + 0     + o0);
      s16x8 bl0 = *(const s16x8*)(smem + 16384 + o0);
      s16x8 bh1 = *(const s16x8*)(smem + 0     + o1);
      s16x8 bl1 = *(const s16x8*)(smem + 16384 + o1);
      s0 = __builtin_amdgcn_mfma_f32_16x16x32_bf16(qh[ks], bh0, s0, 0,0,0);
      s1 = __builtin_amdgcn_mfma_f32_16x16x32_bf16(qh[ks], bh1, s1, 0,0,0);
      s0 = __builtin_amdgcn_mfma_f32_16x16x32_bf16(ql[ks], bh0, s0, 0,0,0);
      s1 = __builtin_amdgcn_mfma_f32_16x16x32_bf16(ql[ks], bh1, s1, 0,0,0);
      s0 = __builtin_amdgcn_mfma_f32_16x16x32_bf16(qh[ks], bl0, s0, 0,0,0);
      s1 = __builtin_amdgcn_mfma_f32_16x16x32_bf16(qh[ks], bl1, s1, 0,0,0);
    }

    float scl[4];
    #pragma unroll
    for (int r = 0; r < 4; ++r){
      float v = fmaxf(s0[r], s1[r]);
      v = fmaxf(v, __shfl_xor(v, 1)); v = fmaxf(v, __shfl_xor(v, 2));
      v = fmaxf(v, __shfl_xor(v, 4)); v = fmaxf(v, __shfl_xor(v, 8));
      float mo = m_run[r];
      float mn = fmaxf(mo, v);
      m_run[r] = mn;
      float sc = __expf(mo - mn);
      scl[r] = sc;
      float p0 = __expf(s0[r] - mn);
      float p1 = __expf(s1[r] - mn);
      float ps = p0 + p1;
      ps += __shfl_xor(ps, 1); ps += __shfl_xor(ps, 2);
      ps += __shfl_xor(ps, 4); ps += __shfl_xor(ps, 8);
      l_run[r] = l_run[r]*sc + ps;
      int q = 16*wid + 4*g + r;
      int pb = q*64;
      *(short*)(smem + 49152 + pb + (( 2*c     ) ^ (r<<4))) = (short)f2bf(p0);
      *(short*)(smem + 49152 + pb + ((32 + 2*c ) ^ (r<<4))) = (short)f2bf(p1);
    }
    #pragma unroll
    for (int dt = 0; dt < 16; ++dt){
      o[dt][0] *= scl[0]; o[dt][1] *= scl[1]; o[dt][2] *= scl[2]; o[dt][3] *= scl[3];
    }

    {
      int q = 16*wid + c;
      s16x8 pa = *(const s16x8*)(smem + 49152 + q*64 + ((16*g) ^ ((q&3)<<4)));
      #pragma unroll
      for (int dt = 0; dt < 16; ++dt){
        int vrow = 16*dt + c;
        s16x8 vb = *(const s16x8*)(smem + 32768 + vrow*64 + ((16*g) ^ (((vrow>>2)&3)<<4)));
        o[dt] = __builtin_amdgcn_mfma_f32_16x16x32_bf16(pa, vb, o[dt], 0,0,0);
      }
    }
  }

  __syncthreads();
  {
    float inv[4];
    #pragma unroll
    for (int r = 0; r < 4; ++r) inv[r] = 1.0f / l_run[r];
    #pragma unroll
    for (int dt = 0; dt < 16; ++dt){
      #pragma unroll
      for (int r = 0; r < 4; ++r){
        int q = 16*wid + 4*g + r;
        int dcol = 16*dt + c;
        float val = o[dt][r] * inv[r];
        *(short*)(smem + 0 + q*512 + ((2*dcol) ^ ((q&7)<<4))) = (short)f2bf(val);
      }
    }
  }

  f32x4 fa[8];
  #pragma unroll
  for (int i = 0; i < 8; ++i) fa[i] = (f32x4){0.f,0.f,0.f,0.f};

  #pragma unroll
  for (int fc = 0; fc < 8; ++fc){
    __syncthreads();
    #pragma unroll
    for (int p = 0; p < 8; ++p){
      int h  = p*16 + (tid >> 4);
      int fl = (tid & 15) * 8;
      const float* srcw = Wm + (size_t)h*1024 + fc*128 + fl;
      float4 x0 = *(const float4*)srcw;
      float4 x1 = *(const float4*)(srcw + 4);
      s16x8 w8;
      w8[0]=(short)f2bf(x0.x); w8[1]=(short)f2bf(x0.y); w8[2]=(short)f2bf(x0.z); w8[3]=(short)f2bf(x0.w);
      w8[4]=(short)f2bf(x1.x); w8[5]=(short)f2bf(x1.y); w8[6]=(short)f2bf(x1.z); w8[7]=(short)f2bf(x1.w);
      *(s16x8*)(smem + 32768 + h*256 + ((2*fl) ^ ((h&7)<<4))) = w8;
    }
    __syncthreads();
    #pragma unroll
    for (int ks = 0; ks < 4; ++ks){
      const int cidx = (fc & 1)*4 + ks;
      s16x8 a;
      if (fc < 2){
        a = qh[cidx];
      } else {
        int q = 16*wid + c;
        s16x8 o8 = *(const s16x8*)(smem + 0 + q*512 + ((64*cidx + 16*g) ^ ((q&7)<<4)));
        if (fc < 4){ a = o8; }
        else {
          #pragma unroll
          for (int j = 0; j < 8; ++j){
            float qf = bf2f((unsigned short)qh[cidx][j]) + bf2f((unsigned short)ql[cidx][j]);
            float of = bf2f((unsigned short)o8[j]);
            float fv = (fc < 6) ? (qf - of) : (qf * of);
            a[j] = (short)f2bf(fv);
          }
        }
      }
      #pragma unroll
      for (int nt = 0; nt < 8; ++nt){
        int hh = 16*nt + c;
        s16x8 wb = *(const s16x8*)(smem + 32768 + hh*256 + ((64*ks + 16*g) ^ ((hh&7)<<4)));
        fa[nt] = __builtin_amdgcn_mfma_f32_16x16x32_bf16(a, wb, fa[nt], 0,0,0);
      }
    }
  }

  #pragma unroll
  for (int nt = 0; nt < 8; ++nt){
    float bs = bia[16*nt + c];
    #pragma unroll
    for (int r = 0; r < 4; ++r){
      int q = 16*wid + 4*g + r;
      float v = fa[nt][r] + bs;
      v = fmaxf(v, 0.f);
      outp[(size_t)q*NH + 16*nt + c] = v;
    }
  }
}

extern "C" void kernel_launch(void* const* d_in, const int* in_sizes, int n_in,
                              void* d_out, int out_size, void* d_ws, size_t ws_size,
                              hipStream_t stream) {
  (void)in_sizes; (void)n_in; (void)out_size;
  const float* cs = (const float*)d_in[0];
  const float* rs = (const float*)d_in[1];
  const float* W1 = (const float*)d_in[2];
  const float* b1 = (const float*)d_in[3];
  const float* W2 = (const float*)d_in[4];
  const float* b2 = (const float*)d_in[5];
  float* out = (float*)d_out;

  if (ws_size >= WS_NEED){
    unsigned char* ws = (unsigned char*)d_ws;
    hipLaunchKernelGGL(prep_rows, dim3(20608), dim3(256), 0, stream, cs, rs, W1, W2, ws);
    hipLaunchKernelGGL(prep_T,    dim3(2560),  dim3(256), 0, stream, cs, rs, ws);
    hipLaunchKernelGGL(lm_main,   dim3(640),   dim3(512), 0, stream, ws, b1, b2, out);
  } else {
    hipLaunchKernelGGL(lm_fallback, dim3(1280), dim3(256), 0, stream,
                       cs, rs, W1, b1, W2, b2, out);
  }
}